// Round 13
// baseline (149.537 us; speedup 1.0000x reference)
//
#include <hip/hip_runtime.h>
#include <hip/hip_bf16.h>

// ---------------- problem constants ----------------
#define BB   4
#define CIN  256
#define CI   64
#define COUT 256
#define NPIX 4096          // 64*64
#define LOG2E 1.44269504088896340736f

// ---------------- ws layout (BYTE offsets) ----------------
#define B_Y1V    0x0000000u  // 4MB: conv1-p0 f32 -> {V bf16 @0, SPREP_SC bf16 @2MB} -> SAPREP bf16 @0
#define B_FEAT1  0x0400000u  // 4MB f32 feat1; later conv2b-p0
#define B_SA     0x0800000u  // 4MB: xprep head; SCFEAT f32; conv2b-p1 (in-place SCCONV)
#define B_Y2     0x0C00000u  // 4MB: xprep tail; PO head; conv2a-p0
#define B_SACONV 0x1000000u  // 4MB: conv1-p1; GP f32; PO tail; conv2a-p1 (in-place SACONV)
#define B_Q      0x1400000u  // 256KB bf16[131072] (q, LOG2E-prescaled)
#define B_K      0x1480000u  // 256KB bf16
#define B_ST     0x15A0000u  // 1.5KB f32[384]
#define B_CATT   0x15B1000u  // 64KB
#define B_WP1    0x15C1000u  // 288KB bf16[147456]
#define B_WP2    0x1610000u  // 72KB  bf16[36864]
#define B_PL     0x1630000u  // 64KB f32[16384] partial-l accumulator
#define B_W8P    0x1640000u  // 32KB bf16[16384]
#define B_WQKV   0x1648000u  // 10KB bf16[5120]
#define B_BALL   0x164B000u  // 320B f32[80]

typedef __attribute__((ext_vector_type(8))) short bf16x8;
typedef __attribute__((ext_vector_type(4))) short bf16x4;
typedef __attribute__((ext_vector_type(4))) float f32x4;

__device__ __forceinline__ short f2bs(float f) {
    union { float f; unsigned u; } c; c.f = f;
    unsigned r = c.u + 0x7FFFu + ((c.u >> 16) & 1u);
    return (short)(r >> 16);
}
__device__ __forceinline__ float bs2f(unsigned short s) {
    union { unsigned u; float f; } c; c.u = ((unsigned)s) << 16;
    return c.f;
}
__device__ __forceinline__ int swz(int wp) { return (wp ^ (wp >> 2)) & 3; }

// ---------------- bodies ----------------

// weight-prep + zeroing (870 virtual blocks)
__device__ __forceinline__ void weights_body(const float* __restrict__ w1,
                                             const float* __restrict__ w2,
                                             const float* __restrict__ w8,
                                             const float* wq, const float* bq,
                                             const float* wk, const float* bk,
                                             const float* wv, const float* bv,
                                             short* wp1, short* wp2, short* w8p,
                                             short* wall, float* ball,
                                             float* st, float* pl, int blk, int t) {
    if (blk < 576) {
        int idx = blk * 256 + t;
        if (idx < 147456) {
            int cil = idx & 31, co = (idx >> 5) & 63;
            int rest = idx >> 11, tap = rest % 9, ch = rest / 9;
            wp1[idx] = f2bs(w1[co * CIN * 9 + (ch * 32 + cil) * 9 + tap]);
        }
    } else if (blk < 720) {
        int idx = (blk - 576) * 256 + t;
        if (idx < 36864) {
            int cil = idx & 31, co = (idx >> 5) & 63;
            int rest = idx >> 11, tap = rest % 9, ch = rest / 9;
            wp2[idx] = f2bs(w2[co * CI * 9 + (ch * 32 + cil) * 9 + tap]);
        }
    } else if (blk < 784) {
        int idx = (blk - 720) * 256 + t;
        w8p[idx] = f2bs(w8[idx]);
    } else if (blk < 804) {
        int idx = (blk - 784) * 256 + t;
        if (idx < 5120) {
            int co = idx >> 6, ci = idx & 63;
            float v;
            if (co < 8)       v = wq[co * 64 + ci] * LOG2E;
            else if (co < 16) v = wk[(co - 8) * 64 + ci];
            else              v = wv[(co - 16) * 64 + ci];
            wall[idx] = f2bs(v);
        }
        if (idx < 80) {
            float v;
            if (idx < 8)       v = bq[idx] * LOG2E;
            else if (idx < 16) v = bk[idx - 8];
            else               v = bv[idx - 16];
            ball[idx] = v;
        }
    } else if (blk < 806) {
        int idx = (blk - 804) * 256 + t;
        if (idx < 384) st[idx] = 0.f;
    } else {
        int idx = (blk - 806) * 256 + t;
        pl[idx] = 0.f;
    }
}

// transpose f32 [b][NCH*32 ci][4096] -> bf16 [b][NCH][h][w][ci32]
template<int NCH>
__device__ __forceinline__ void prep_body(const float* __restrict__ in,
                                          short* __restrict__ out, int blk, int t) {
    __shared__ short tl[4][64][34];
    int hq = blk & 15;
    int ch = (blk >> 4) % NCH;
    int b  = blk / (16 * NCH);
    const int CINT = NCH * 32;

    #pragma unroll
    for (int i = 0; i < 32; ++i) {
        int idx = i * 256 + t;
        int w = idx & 63, hh = (idx >> 6) & 3, ci = idx >> 8;
        float v = in[((size_t)(b * CINT + ch * 32 + ci)) * NPIX + (hq * 4 + hh) * 64 + w];
        tl[hh][w][ci] = f2bs(v);
    }
    __syncthreads();
    unsigned* outu = (unsigned*)(out + (((size_t)(b * NCH + ch)) * NPIX + hq * 4 * 64) * 32);
    #pragma unroll
    for (int i = 0; i < 16; ++i) {
        int j = i * 256 + t;
        int cip = j & 15, w = (j >> 4) & 63, hh = j >> 10;
        unsigned v = *(unsigned*)&tl[hh][w][2 * cip];
        outu[(size_t)(hh * 64 + w) * 16 + cip] = v;
    }
}

// fused weights + prep<8>
__global__ __launch_bounds__(256) void k_prepw(const float* __restrict__ x,
                                               const float* w1, const float* w2, const float* w8,
                                               const float* wq, const float* bq,
                                               const float* wk, const float* bk,
                                               const float* wv, const float* bv,
                                               short* xprep,
                                               short* wp1, short* wp2, short* w8p,
                                               short* wall, float* ball,
                                               float* st, float* pl) {
    int blk = blockIdx.x, t = threadIdx.x;
    if (blk < 512) prep_body<8>(x, xprep, blk, t);
    else weights_body(w1, w2, w8, wq, bq, wk, bk, wv, bv,
                      wp1, wp2, w8p, wall, ball, st, pl, blk - 512, t);
}

// PAM-merge + prep: sa = feat1 + g*(sum_jc PO)/PL -> bf16 [b][2][h][w][ci32]
__device__ __forceinline__ void pamprep_body(const short* __restrict__ po,
                                             const float* __restrict__ pl_acc,
                                             const float* __restrict__ feat1,
                                             const float* __restrict__ gp,
                                             short* __restrict__ out, int blk, int t) {
    __shared__ short tl[4][64][34];
    int hq = blk & 15;
    int ch = (blk >> 4) & 1;
    int b  = blk >> 5;
    float g = gp[0];

    #pragma unroll
    for (int i = 0; i < 32; ++i) {
        int idx = i * 256 + t;
        int w = idx & 63, hh = (idx >> 6) & 3, ci = idx >> 8;
        int pix = (hq * 4 + hh) * 64 + w;
        size_t o = ((size_t)(b * 64 + ch * 32 + ci)) * NPIX + pix;
        float s = bs2f((unsigned short)po[o])
                + bs2f((unsigned short)po[o + 1048576])
                + bs2f((unsigned short)po[o + 2097152])
                + bs2f((unsigned short)po[o + 3145728]);
        float v = feat1[o] + g * s / pl_acc[b * NPIX + pix];
        tl[hh][w][ci] = f2bs(v);
    }
    __syncthreads();
    unsigned* outu = (unsigned*)(out + (((size_t)(b * 2 + ch)) * NPIX + hq * 4 * 64) * 32);
    #pragma unroll
    for (int i = 0; i < 16; ++i) {
        int j = i * 256 + t;
        int cip = j & 15, w = (j >> 4) & 63, hh = j >> 10;
        unsigned v = *(unsigned*)&tl[hh][w][2 * cip];
        outu[(size_t)(hh * 64 + w) * 16 + cip] = v;
    }
}

// fused prep<2>(scfeat) + pamprep
__global__ __launch_bounds__(256) void k_preppam(const float* __restrict__ scfeat,
                                                 short* __restrict__ sprep_sc,
                                                 const short* __restrict__ po,
                                                 const float* __restrict__ pl_acc,
                                                 const float* __restrict__ feat1,
                                                 const float* __restrict__ gp,
                                                 short* __restrict__ saprep) {
    int blk = blockIdx.x, t = threadIdx.x;
    if (blk < 128) prep_body<2>(scfeat, sprep_sc, blk, t);
    else pamprep_body(po, pl_acc, feat1, gp, saprep, blk - 128, t);
}

// 3x3 SAME conv via MFMA, K-split body: blk in [0,512): ks=blk>>8, b, h
template<int NCH>
__device__ __forceinline__ void conv_body(const short* __restrict__ xprep,
                                          const short* __restrict__ wp,
                                          float* __restrict__ y0,
                                          float* __restrict__ y1,
                                          int blk, int t) {
    __shared__ __align__(16) short xl[3][66][32];
    int lane = t & 63, wv = t >> 6;
    int ks = blk >> 8;
    int b = (blk >> 6) & 3, h = blk & 63;
    int g = lane >> 4, n16 = lane & 15;
    constexpr int NH = NCH / 2;
    int c0 = ks * NH;

    if (t < 24) {
        int r = t >> 3, cc = ((t >> 2) & 1) ? 65 : 0, u = t & 3;
        bf16x8 z = {};
        *(bf16x8*)&xl[r][cc][u * 8] = z;
    }

    f32x4 acc[4];
    #pragma unroll
    for (int i = 0; i < 4; ++i) acc[i] = (f32x4){0.f, 0.f, 0.f, 0.f};

    int sw = t >> 2, su = t & 3;
    int spu = su ^ swz(sw + 1);

    for (int ch = c0; ch < c0 + NH; ++ch) {
        __syncthreads();
        #pragma unroll
        for (int r = 0; r < 3; ++r) {
            int hh = h + r - 1;
            bf16x8 v = {};
            if (hh >= 0 && hh < 64)
                v = *(const bf16x8*)(xprep + (((size_t)(b * NCH + ch)) * 64 + hh) * 64 * 32 + sw * 32 + su * 8);
            *(bf16x8*)&xl[r][sw + 1][spu * 8] = v;
        }
        __syncthreads();

        const short* wbase = wp + ((size_t)(ch * 9)) * 64 * 32;
        #pragma unroll
        for (int tap = 0; tap < 9; ++tap) {
            int kr = tap / 3, kc = tap % 3;
            bf16x8 a = *(const bf16x8*)(wbase + ((size_t)(tap * 64 + wv * 16 + n16)) * 32 + g * 8);
            #pragma unroll
            for (int nt = 0; nt < 4; ++nt) {
                int wpix = nt * 16 + n16 + kc;
                int pu = g ^ swz(wpix);
                bf16x8 bx = *(const bf16x8*)&xl[kr][wpix][pu * 8];
                acc[nt] = __builtin_amdgcn_mfma_f32_16x16x32_bf16(a, bx, acc[nt], 0, 0, 0);
            }
        }
    }

    float* y = ks ? y1 : y0;
    #pragma unroll
    for (int nt = 0; nt < 4; ++nt) {
        #pragma unroll
        for (int r = 0; r < 4; ++r) {
            int co = wv * 16 + g * 4 + r;
            y[((size_t)(b * CI + co)) * NPIX + h * 64 + nt * 16 + n16] = acc[nt][r];
        }
    }
}

template<int NCH>
__global__ __launch_bounds__(256) void k_convmfma(const short* __restrict__ xprep,
                                                  const short* __restrict__ wp,
                                                  float* __restrict__ y0,
                                                  float* __restrict__ y1) {
    conv_body<NCH>(xprep, wp, y0, y1, blockIdx.x, threadIdx.x);
}

// both conv2's in one dispatch
__global__ __launch_bounds__(256) void k_conv2x(const short* __restrict__ inA,
                                                const short* __restrict__ inB,
                                                const short* __restrict__ wp,
                                                float* a0, float* a1,
                                                float* b0, float* b1) {
    int blk = blockIdx.x;
    int w = blk >> 9;
    conv_body<2>(w ? inB : inA, wp, w ? b0 : a0, w ? b1 : a1, blk & 511, threadIdx.x);
}

// BN stats from two conv partials
__device__ __forceinline__ void bnstats_body(const float* __restrict__ y0,
                                             const float* __restrict__ y1,
                                             float* stats, int blk, int t) {
    int c = blk >> 2, b = blk & 3;
    size_t base = ((size_t)(b * 64 + c)) * NPIX;
    float s = 0.f, sq = 0.f;
    for (int i = t; i < NPIX; i += 256) {
        float v = y0[base + i] + y1[base + i];
        s += v; sq += v * v;
    }
    __shared__ float rs[8];
    for (int o = 32; o; o >>= 1) { s += __shfl_down(s, o); sq += __shfl_down(sq, o); }
    if ((t & 63) == 0) { rs[t >> 6] = s; rs[4 + (t >> 6)] = sq; }
    __syncthreads();
    if (t == 0) {
        atomicAdd(&stats[c], rs[0] + rs[1] + rs[2] + rs[3]);
        atomicAdd(&stats[64 + c], rs[4] + rs[5] + rs[6] + rs[7]);
    }
}

__global__ __launch_bounds__(256) void k_bnstats(const float* y0, const float* y1, float* stats) {
    bnstats_body(y0, y1, stats, blockIdx.x, threadIdx.x);
}
__global__ __launch_bounds__(256) void k_bnstats2x(const float* a0, const float* a1,
                                                   const float* b0, const float* b1,
                                                   float* sta, float* stb) {
    int blk = blockIdx.x;
    int w = blk >> 8;
    bnstats_body(w ? b0 : a0, w ? b1 : a1, w ? stb : sta, blk & 255, threadIdx.x);
}

__device__ __forceinline__ void bnapply_body(const float* y0, const float* y1,
                                             const float* stats, const float* g,
                                             const float* bta, float* out, int i) {
    int c = (i >> 12) & 63;
    float mean = stats[c] * (1.f / 16384.f);
    float var = stats[64 + c] * (1.f / 16384.f) - mean * mean;
    float rs = rsqrtf(var + 1e-5f);
    float v = (y0[i] + y1[i] - mean) * rs * g[c] + bta[c];
    out[i] = v > 0.f ? v : 0.f;
}

__global__ __launch_bounds__(256) void k_bnapply2(const float* y0, const float* y1,
                                                  const float* stats, const float* g,
                                                  const float* bta, float* out) {
    bnapply_body(y0, y1, stats, g, bta, out, blockIdx.x * 256 + threadIdx.x);
}
__global__ __launch_bounds__(256) void k_bnapply2x(const float* a0, const float* a1,
                                                   const float* b0, const float* b1,
                                                   const float* sta, const float* stb,
                                                   const float* g, const float* bta,
                                                   float* oa, float* ob) {
    int blk = blockIdx.x;
    int w = blk >> 12;
    int i = (blk & 4095) * 256 + threadIdx.x;
    bnapply_body(w ? b0 : a0, w ? b1 : a1, w ? stb : sta, g, bta, w ? ob : oa, i);
}

// q/k/v via MFMA body (256 virtual blocks)
__device__ __forceinline__ void qkv_body(const float* __restrict__ feat1,
                                         const short* __restrict__ wall,
                                         const float* __restrict__ ball,
                                         short* __restrict__ q,
                                         short* __restrict__ k,
                                         short* __restrict__ v, int blk, int t) {
    __shared__ __align__(16) short fl[64][64];
    int lane = t & 63, wv = t >> 6;
    int h = blk & 63, b = blk >> 6;
    int n16 = lane & 15, g = lane >> 4;

    {
        int n = t & 63, ug2 = t >> 6;
        const float* fp = feat1 + ((size_t)b * CI) * NPIX + h * 64 + n;
        #pragma unroll
        for (int uu = 0; uu < 2; ++uu) {
            int u = ug2 + uu * 4;
            int ci0 = u * 8;
            short tmp[8];
            #pragma unroll
            for (int j = 0; j < 8; ++j) tmp[j] = f2bs(fp[(size_t)(ci0 + j) * NPIX]);
            int phys = u ^ (n & 7);
            *(bf16x8*)&fl[n][phys * 8] = *(bf16x8*)tmp;
        }
    }
    __syncthreads();

    f32x4 acc[4];
    #pragma unroll
    for (int i = 0; i < 4; ++i) acc[i] = (f32x4){0.f, 0.f, 0.f, 0.f};
    f32x4 acc4 = (f32x4){0.f, 0.f, 0.f, 0.f};

    #pragma unroll
    for (int kc = 0; kc < 2; ++kc) {
        bf16x8 a = *(const bf16x8*)&wall[(size_t)(wv * 16 + n16) * 64 + kc * 32 + g * 8];
        bf16x8 a4 = *(const bf16x8*)&wall[(size_t)(64 + n16) * 64 + kc * 32 + g * 8];
        #pragma unroll
        for (int nt = 0; nt < 4; ++nt) {
            int n = nt * 16 + n16;
            int phys = (kc * 4 + g) ^ (n & 7);
            bf16x8 bx = *(const bf16x8*)&fl[n][phys * 8];
            acc[nt] = __builtin_amdgcn_mfma_f32_16x16x32_bf16(a, bx, acc[nt], 0, 0, 0);
            if (nt == wv) acc4 = __builtin_amdgcn_mfma_f32_16x16x32_bf16(a4, bx, acc4, 0, 0, 0);
        }
    }

    #pragma unroll
    for (int nt = 0; nt < 4; ++nt) {
        int pix = h * 64 + nt * 16 + n16;
        #pragma unroll
        for (int r = 0; r < 4; ++r) {
            int co = wv * 16 + g * 4 + r;
            short val = f2bs(acc[nt][r] + ball[co]);
            if (co < 8)       q[((size_t)(b * 8 + co)) * NPIX + pix] = val;
            else if (co < 16) k[((size_t)(b * 8 + co - 8)) * NPIX + pix] = val;
            else              v[((size_t)(b * 64 + co - 16)) * NPIX + pix] = val;
        }
    }
    {
        int pix = h * 64 + wv * 16 + n16;
        #pragma unroll
        for (int r = 0; r < 4; ++r) {
            int co = 64 + g * 4 + r;
            v[((size_t)(b * 64 + co - 16)) * NPIX + pix] = f2bs(acc4[r] + ball[co]);
        }
    }
}

// CAM gram partials body (256 virtual blocks)
__device__ __forceinline__ void gram_body(const float* __restrict__ f,
                                          float* __restrict__ gp, int blk, int t) {
    __shared__ __align__(16) float fl[64 * 68];
    int b = blk >> 6, nc = blk & 63;
    int n0 = nc * 64;
    int c = t & 63, dg = t >> 6;
    float acc[16];
    #pragma unroll
    for (int i = 0; i < 16; ++i) acc[i] = 0.f;
    for (int idx = t; idx < 4096; idx += 256) {
        int cc = idx >> 6, nn = idx & 63;
        fl[nn * 68 + cc] = f[((size_t)b * 64 + cc) * NPIX + n0 + nn];
    }
    __syncthreads();
    for (int nn = 0; nn < 64; ++nn) {
        float fc = fl[nn * 68 + c];
        const float4* fd = (const float4*)(fl + nn * 68 + dg * 16);
        #pragma unroll
        for (int k4 = 0; k4 < 4; ++k4) {
            float4 vv = fd[k4];
            acc[k4 * 4 + 0] += fc * vv.x;
            acc[k4 * 4 + 1] += fc * vv.y;
            acc[k4 * 4 + 2] += fc * vv.z;
            acc[k4 * 4 + 3] += fc * vv.w;
        }
    }
    float* dst = gp + (size_t)nc * 16384 + ((size_t)b * 64 + c) * 64 + dg * 16;
    #pragma unroll
    for (int kk = 0; kk < 16; ++kk) dst[kk] = acc[kk];
}

// fused qkv + gram (both read feat1 only)
__global__ __launch_bounds__(256) void k_qkvgram(const float* __restrict__ feat1,
                                                 const short* __restrict__ wall,
                                                 const float* __restrict__ ball,
                                                 short* q, short* k, short* v,
                                                 float* gp) {
    int blk = blockIdx.x, t = threadIdx.x;
    if (blk < 256) qkv_body(feat1, wall, ball, q, k, v, blk, t);
    else gram_body(feat1, gp, blk - 256, t);
}

// PAM partial pass, KVBLK=256, conflict-free kl + XOR-swizzled pl.
__global__ __launch_bounds__(256) void k_pampart(const short* __restrict__ q,
                                                 const short* __restrict__ k,
                                                 const short* __restrict__ v,
                                                 short* __restrict__ po,
                                                 float* __restrict__ pl_acc) {
    __shared__ __align__(16) short kl[256][8];   // [j][d0..7], 16B rows
    __shared__ __align__(16) short pl[64][272];  // [i][j 256], 16B-unit XOR swizzle

    int t = threadIdx.x;
    int lane = t & 63, w = t >> 6;
    int blk = blockIdx.x;
    int jc = blk >> 8, b = (blk >> 6) & 3, ic = blk & 63;
    int i0 = ic * 64;
    int n16 = lane & 15, g = lane >> 4;
    int key = n16 & 7;

    const short* qb = q + (size_t)b * 8 * NPIX;
    const short* kb = k + (size_t)b * 8 * NPIX;
    const short* vb = v + (size_t)b * 64 * NPIX;

    // aq as B-operand: lane<16 holds q[d=e][i0+w*16+lane]
    bf16x8 aq = {};
    if (lane < 16) {
        int irow = i0 + w * 16 + lane;
        #pragma unroll
        for (int e = 0; e < 8; ++e) aq[e] = qb[(size_t)e * NPIX + irow];
    }

    f32x4 acc[4];
    #pragma unroll
    for (int i = 0; i < 4; ++i) acc[i] = (f32x4){0.f, 0.f, 0.f, 0.f};
    float lacc = 0.f;
    const f32x4 zz = {0.f, 0.f, 0.f, 0.f};

    for (int ro = 0; ro < 4; ++ro) {
        int j0 = jc * 1024 + ro * 256;
        // stage K (256j x 8d): idx -> row=idx>>2, col=idx&3 (conflict-free u32)
        #pragma unroll
        for (int it = 0; it < 4; ++it) {
            int idx = it * 256 + t;
            int row = idx >> 2, col = idx & 3;
            unsigned lo = (unsigned short)kb[(size_t)(2 * col) * NPIX + j0 + row];
            unsigned hi = (unsigned short)kb[(size_t)(2 * col + 1) * NPIX + j0 + row];
            *(unsigned*)&kl[row][col * 2] = lo | (hi << 16);
        }
        // V fragments direct from global (issue early)
        bf16x8 av[8];
        #pragma unroll
        for (int ks = 0; ks < 8; ++ks)
            av[ks] = *(const bf16x8*)&vb[(size_t)(w * 16 + n16) * NPIX + j0 + ks * 32 + g * 8];
        __syncthreads();

        // swapped QK: mfma(K,Q) -> D[j][i]; lane holds 4 consecutive j at col i=n16
        #pragma unroll
        for (int jsub = 0; jsub < 16; ++jsub) {
            bf16x8 bk = {};
            if (lane < 16) bk = *(const bf16x8*)&kl[jsub * 16 + n16][0];
            f32x4 s = __builtin_amdgcn_mfma_f32_16x16x32_bf16(bk, aq, zz, 0, 0, 0);
            float e0 = exp2f(s[0]), e1 = exp2f(s[1]), e2 = exp2f(s[2]), e3 = exp2f(s[3]);
            lacc += (e0 + e1) + (e2 + e3);
            bf16x4 pk = { f2bs(e0), f2bs(e1), f2bs(e2), f2bs(e3) };
            int uw = (jsub * 2 + (g >> 1)) ^ key;           // 16B unit, XOR swizzle
            *(bf16x4*)&pl[w * 16 + n16][uw * 8 + (g & 1) * 4] = pk;
        }
        __syncthreads();

        // O^T += V * P^T (32 MFMA)
        #pragma unroll
        for (int isub = 0; isub < 4; ++isub) {
            #pragma unroll
            for (int ks = 0; ks < 8; ++ks) {
                int ur = (ks * 4 + g) ^ key;
                bf16x8 bp = *(const bf16x8*)&pl[isub * 16 + n16][ur * 8];
                acc[isub] = __builtin_amdgcn_mfma_f32_16x16x32_bf16(av[ks], bp, acc[isub], 0, 0, 0);
            }
        }
        __syncthreads();
    }

    // l reduce: lanes {n16, n16+16, n16+32, n16+48} share row i0+w*16+n16
    {
        float lv = lacc;
        lv += __shfl_xor(lv, 16);
        lv += __shfl_xor(lv, 32);
        if (lane < 16)
            atomicAdd(&pl_acc[b * NPIX + i0 + w * 16 + lane], lv);
    }

    #pragma unroll
    for (int isub = 0; isub < 4; ++isub) {
        #pragma unroll
        for (int r = 0; r < 4; ++r) {
            int c = w * 16 + g * 4 + r;
            size_t o = ((size_t)((jc * BB + b) * 64 + c)) * NPIX + i0 + isub * 16 + n16;
            po[o] = f2bs(acc[isub][r]);
        }
    }
}

// fused gram-reduce + channel softmax
__global__ void k_camsm2(const float* __restrict__ gp, float* __restrict__ cattn) {
    int row = blockIdx.x;
    int d = threadIdx.x;
    float v = 0.f;
    #pragma unroll 8
    for (int p = 0; p < 64; ++p) v += gp[(size_t)p * 16384 + row * 64 + d];
    float mn = v;
    for (int s = 32; s; s >>= 1) mn = fminf(mn, __shfl_xor(mn, s));
    float e = exp2f((mn - v) * LOG2E);
    float sum = e;
    for (int s = 32; s; s >>= 1) sum += __shfl_xor(sum, s);
    cattn[(size_t)row * 64 + d] = e / sum;
}

// sc_feat = gamma_cam * (cattn @ f) + feat1
__global__ __launch_bounds__(256) void k_cam(const float* __restrict__ cattn,
                                             const float* __restrict__ f,
                                             const float* __restrict__ gcp,
                                             float* __restrict__ sc) {
    __shared__ __align__(16) float Al[64 * 68];
    __shared__ float fl[64 * 64];
    int blk = blockIdx.x;
    int b = blk >> 6, nc = blk & 63;
    int n0 = nc * 64;
    int t = threadIdx.x;
    int nl = t & 63, cg = t >> 6;
    for (int idx = t; idx < 4096; idx += 256) {
        int cc = idx >> 6, dd = idx & 63;
        Al[dd * 68 + cc] = cattn[((size_t)b * 64 + cc) * 64 + dd];
    }
    for (int idx = t; idx < 4096; idx += 256) {
        int dd = idx >> 6, nn = idx & 63;
        fl[dd * 64 + nn] = f[((size_t)b * 64 + dd) * NPIX + n0 + nn];
    }
    __syncthreads();
    float acc[16];
    #pragma unroll
    for (int i = 0; i < 16; ++i) acc[i] = 0.f;
    for (int d = 0; d < 64; ++d) {
        float fv = fl[d * 64 + nl];
        const float4* A4 = (const float4*)(Al + d * 68 + cg * 16);
        #pragma unroll
        for (int k4 = 0; k4 < 4; ++k4) {
            float4 a = A4[k4];
            acc[k4 * 4 + 0] += a.x * fv;
            acc[k4 * 4 + 1] += a.y * fv;
            acc[k4 * 4 + 2] += a.z * fv;
            acc[k4 * 4 + 3] += a.w * fv;
        }
    }
    float g = gcp[0];
    #pragma unroll
    for (int kk = 0; kk < 16; ++kk) {
        int c = cg * 16 + kk;
        size_t o = ((size_t)b * 64 + c) * NPIX + n0 + nl;
        sc[o] = g * acc[kk] + f[o];
    }
}

// out = w8 @ (sa_conv + sc_conv) + b8 via MFMA (1x1, 64 -> 256)
__global__ __launch_bounds__(256) void k_finalmfma(const float* __restrict__ sa,
                                                   const float* __restrict__ sc,
                                                   const short* __restrict__ w8p,
                                                   const float* __restrict__ b8,
                                                   float* __restrict__ out) {
    __shared__ __align__(16) short fl[64][64];
    int t = threadIdx.x;
    int lane = t & 63, wv = t >> 6;
    int blk = blockIdx.x;
    int h = blk & 63, b = (blk >> 6) & 3, cq = blk >> 8;
    int n16 = lane & 15, g = lane >> 4;

    {
        int n = t & 63, ug2 = t >> 6;
        const float* sap = sa + ((size_t)b * CI) * NPIX + h * 64 + n;
        const float* scp = sc + ((size_t)b * CI) * NPIX + h * 64 + n;
        #pragma unroll
        for (int uu = 0; uu < 2; ++uu) {
            int u = ug2 + uu * 4;
            int ci0 = u * 8;
            short tmp[8];
            #pragma unroll
            for (int j = 0; j < 8; ++j) {
                size_t o = (size_t)(ci0 + j) * NPIX;
                tmp[j] = f2bs(sap[o] + scp[o]);
            }
            int phys = u ^ (n & 7);
            *(bf16x8*)&fl[n][phys * 8] = *(bf16x8*)tmp;
        }
    }
    __syncthreads();

    f32x4 acc[4];
    #pragma unroll
    for (int i = 0; i < 4; ++i) acc[i] = (f32x4){0.f, 0.f, 0.f, 0.f};
    int cobase = cq * 64 + wv * 16;

    #pragma unroll
    for (int kc = 0; kc < 2; ++kc) {
        bf16x8 a = *(const bf16x8*)&w8p[(size_t)(cobase + n16) * 64 + kc * 32 + g * 8];
        #pragma unroll
        for (int nt = 0; nt < 4; ++nt) {
            int n = nt * 16 + n16;
            int phys = (kc * 4 + g) ^ (n & 7);
            bf16x8 bx = *(const bf16x8*)&fl[n][phys * 8];
            acc[nt] = __builtin_amdgcn_mfma_f32_16x16x32_bf16(a, bx, acc[nt], 0, 0, 0);
        }
    }

    #pragma unroll
    for (int nt = 0; nt < 4; ++nt) {
        #pragma unroll
        for (int r = 0; r < 4; ++r) {
            int co = cobase + g * 4 + r;
            out[((size_t)(b * COUT + co)) * NPIX + h * 64 + nt * 16 + n16] = acc[nt][r] + b8[co];
        }
    }
}

// ---------------- launcher ----------------
extern "C" void kernel_launch(void* const* d_in, const int* in_sizes, int n_in,
                              void* d_out, int out_size, void* d_ws, size_t ws_size,
                              hipStream_t stream) {
    (void)in_sizes; (void)n_in; (void)out_size; (void)ws_size;
    const float* x    = (const float*)d_in[0];
    const float* w1   = (const float*)d_in[1];
    const float* bng  = (const float*)d_in[2];
    const float* bnb  = (const float*)d_in[3];
    const float* wq   = (const float*)d_in[4];
    const float* bq   = (const float*)d_in[5];
    const float* wk   = (const float*)d_in[6];
    const float* bk   = (const float*)d_in[7];
    const float* wv   = (const float*)d_in[8];
    const float* bv   = (const float*)d_in[9];
    const float* gpam = (const float*)d_in[10];
    const float* gcam = (const float*)d_in[11];
    const float* w2   = (const float*)d_in[12];
    const float* w8   = (const float*)d_in[13];
    const float* b8   = (const float*)d_in[14];
    float* out = (float*)d_out;

    char* WB = (char*)d_ws;
    float* fC1P0   = (float*)(WB + B_Y1V);            // conv1 p0
    float* fC1P1   = (float*)(WB + B_SACONV);         // conv1 p1
    float* fGP     = (float*)(WB + B_SACONV);         // gram partials (4MB, after C1P1 dies)
    short* fV      = (short*)(WB + B_Y1V);            // V bf16 (2MB)
    short* fSPREPSC= (short*)(WB + B_Y1V + 0x200000); // sc-prep bf16 (2MB)
    short* fSAPREP = (short*)(WB + B_Y1V);            // sa-prep bf16 (2MB, after V dies)
    float* fFEAT1  = (float*)(WB + B_FEAT1);
    short* fXPREP  = (short*)(WB + B_SA);             // 8MB spanning SA+Y2
    float* fSCFEAT = (float*)(WB + B_SA);
    float* fC2B1   = (float*)(WB + B_SA);             // conv2b p1; SCCONV in-place
    short* fPO     = (short*)(WB + B_Y2);             // 8MB spanning Y2+SACONV
    float* fC2A0   = (float*)(WB + B_Y2);             // conv2a p0
    float* fC2B0   = (float*)(WB + B_FEAT1);          // conv2b p0 (feat1 dead)
    float* fC2A1   = (float*)(WB + B_SACONV);         // conv2a p1; SACONV in-place
    short* fQ      = (short*)(WB + B_Q);
    short* fK      = (short*)(WB + B_K);
    float* fST     = (float*)(WB + B_ST);
    float* fST2a   = fST + 128;
    float* fST2b   = fST + 256;
    float* fCATT   = (float*)(WB + B_CATT);
    short* fWP1    = (short*)(WB + B_WP1);
    short* fWP2    = (short*)(WB + B_WP2);
    float* fPL     = (float*)(WB + B_PL);
    short* fW8P    = (short*)(WB + B_W8P);
    short* fWQKV   = (short*)(WB + B_WQKV);
    float* fBALL   = (float*)(WB + B_BALL);

    k_prepw<<<1382, 256, 0, stream>>>(x, w1, w2, w8, wq, bq, wk, bk, wv, bv,
                                      fXPREP, fWP1, fWP2, fW8P, fWQKV, fBALL, fST, fPL);

    k_convmfma<8><<<512, 256, 0, stream>>>(fXPREP, fWP1, fC1P0, fC1P1);
    k_bnstats<<<256, 256, 0, stream>>>(fC1P0, fC1P1, fST);
    k_bnapply2<<<4096, 256, 0, stream>>>(fC1P0, fC1P1, fST, bng, bnb, fFEAT1);

    k_qkvgram<<<512, 256, 0, stream>>>(fFEAT1, fWQKV, fBALL, fQ, fK, fV, fGP);
    k_camsm2<<<256, 64, 0, stream>>>(fGP, fCATT);        // GP consumed before PO clobbers it

    k_pampart<<<1024, 256, 0, stream>>>(fQ, fK, fV, fPO, fPL);
    k_cam<<<256, 256, 0, stream>>>(fCATT, fFEAT1, gcam, fSCFEAT);
    k_preppam<<<256, 256, 0, stream>>>(fSCFEAT, fSPREPSC, fPO, fPL, fFEAT1, gpam, fSAPREP);

    k_conv2x<<<1024, 256, 0, stream>>>(fSAPREP, fSPREPSC, fWP2, fC2A0, fC2A1, fC2B0, fC2B1);
    k_bnstats2x<<<512, 256, 0, stream>>>(fC2A0, fC2A1, fC2B0, fC2B1, fST2a, fST2b);
    k_bnapply2x<<<8192, 256, 0, stream>>>(fC2A0, fC2A1, fC2B0, fC2B1, fST2a, fST2b,
                                          bng, bnb, fC2A1, fC2B1);

    k_finalmfma<<<1024, 256, 0, stream>>>(fC2A1, fC2B1, fW8P, b8, out);
}

// Round 14
// 137.105 us; speedup vs baseline: 1.0907x; 1.0907x over previous
//
#include <hip/hip_runtime.h>
#include <hip/hip_bf16.h>

// ---------------- problem constants ----------------
#define BB   4
#define CIN  256
#define CI   64
#define COUT 256
#define NPIX 4096          // 64*64
#define LOG2E 1.44269504088896340736f

// ---------------- ws layout (BYTE offsets) ----------------
#define B_Y1V    0x0000000u  // 4MB: conv1-p0 f32 -> {V bf16 @0, SPREP_SC bf16 @2MB} -> SAPREP bf16 @0
#define B_FEAT1  0x0400000u  // 4MB f32 feat1; later conv2b-p0
#define B_SA     0x0800000u  // 4MB: xprep head; SCFEAT f32; conv2b-p1 (in-place SCCONV)
#define B_Y2     0x0C00000u  // 4MB: xprep tail; PO head; conv2a-p0
#define B_SACONV 0x1000000u  // 4MB: conv1-p1; GP f32; PO tail; conv2a-p1 (in-place SACONV)
#define B_Q      0x1400000u  // 256KB bf16[131072] (q, LOG2E-prescaled)
#define B_K      0x1480000u  // 256KB bf16
#define B_ST     0x15A0000u  // 1.5KB f32[384]
#define B_CATT   0x15B1000u  // 64KB
#define B_WP1    0x15C1000u  // 288KB bf16[147456]
#define B_WP2    0x1610000u  // 72KB  bf16[36864]
#define B_PL     0x1630000u  // 64KB f32[16384] partial-l accumulator
#define B_W8P    0x1640000u  // 32KB bf16[16384]
#define B_WQKV   0x1648000u  // 10KB bf16[5120]
#define B_BALL   0x164B000u  // 320B f32[80]

typedef __attribute__((ext_vector_type(8))) short bf16x8;
typedef __attribute__((ext_vector_type(4))) short bf16x4;
typedef __attribute__((ext_vector_type(4))) float f32x4;

__device__ __forceinline__ short f2bs(float f) {
    union { float f; unsigned u; } c; c.f = f;
    unsigned r = c.u + 0x7FFFu + ((c.u >> 16) & 1u);
    return (short)(r >> 16);
}
__device__ __forceinline__ float bs2f(unsigned short s) {
    union { unsigned u; float f; } c; c.u = ((unsigned)s) << 16;
    return c.f;
}
__device__ __forceinline__ int swz(int wp) { return (wp ^ (wp >> 2)) & 3; }

// ---------------- bodies ----------------

// weight-prep + zeroing (870 virtual blocks)
__device__ __forceinline__ void weights_body(const float* __restrict__ w1,
                                             const float* __restrict__ w2,
                                             const float* __restrict__ w8,
                                             const float* wq, const float* bq,
                                             const float* wk, const float* bk,
                                             const float* wv, const float* bv,
                                             short* wp1, short* wp2, short* w8p,
                                             short* wall, float* ball,
                                             float* st, float* pl, int blk, int t) {
    if (blk < 576) {
        int idx = blk * 256 + t;
        if (idx < 147456) {
            int cil = idx & 31, co = (idx >> 5) & 63;
            int rest = idx >> 11, tap = rest % 9, ch = rest / 9;
            wp1[idx] = f2bs(w1[co * CIN * 9 + (ch * 32 + cil) * 9 + tap]);
        }
    } else if (blk < 720) {
        int idx = (blk - 576) * 256 + t;
        if (idx < 36864) {
            int cil = idx & 31, co = (idx >> 5) & 63;
            int rest = idx >> 11, tap = rest % 9, ch = rest / 9;
            wp2[idx] = f2bs(w2[co * CI * 9 + (ch * 32 + cil) * 9 + tap]);
        }
    } else if (blk < 784) {
        int idx = (blk - 720) * 256 + t;
        w8p[idx] = f2bs(w8[idx]);
    } else if (blk < 804) {
        int idx = (blk - 784) * 256 + t;
        if (idx < 5120) {
            int co = idx >> 6, ci = idx & 63;
            float v;
            if (co < 8)       v = wq[co * 64 + ci] * LOG2E;
            else if (co < 16) v = wk[(co - 8) * 64 + ci];
            else              v = wv[(co - 16) * 64 + ci];
            wall[idx] = f2bs(v);
        }
        if (idx < 80) {
            float v;
            if (idx < 8)       v = bq[idx] * LOG2E;
            else if (idx < 16) v = bk[idx - 8];
            else               v = bv[idx - 16];
            ball[idx] = v;
        }
    } else if (blk < 806) {
        int idx = (blk - 804) * 256 + t;
        if (idx < 384) st[idx] = 0.f;
    } else {
        int idx = (blk - 806) * 256 + t;
        pl[idx] = 0.f;
    }
}

// transpose f32 [b][NCH*32 ci][4096] -> bf16 [b][NCH][h][w][ci32]
template<int NCH>
__device__ __forceinline__ void prep_body(const float* __restrict__ in,
                                          short* __restrict__ out, int blk, int t) {
    __shared__ short tl[4][64][34];
    int hq = blk & 15;
    int ch = (blk >> 4) % NCH;
    int b  = blk / (16 * NCH);
    const int CINT = NCH * 32;

    #pragma unroll
    for (int i = 0; i < 32; ++i) {
        int idx = i * 256 + t;
        int w = idx & 63, hh = (idx >> 6) & 3, ci = idx >> 8;
        float v = in[((size_t)(b * CINT + ch * 32 + ci)) * NPIX + (hq * 4 + hh) * 64 + w];
        tl[hh][w][ci] = f2bs(v);
    }
    __syncthreads();
    unsigned* outu = (unsigned*)(out + (((size_t)(b * NCH + ch)) * NPIX + hq * 4 * 64) * 32);
    #pragma unroll
    for (int i = 0; i < 16; ++i) {
        int j = i * 256 + t;
        int cip = j & 15, w = (j >> 4) & 63, hh = j >> 10;
        unsigned v = *(unsigned*)&tl[hh][w][2 * cip];
        outu[(size_t)(hh * 64 + w) * 16 + cip] = v;
    }
}

// fused weights + prep<8>
__global__ __launch_bounds__(256) void k_prepw(const float* __restrict__ x,
                                               const float* w1, const float* w2, const float* w8,
                                               const float* wq, const float* bq,
                                               const float* wk, const float* bk,
                                               const float* wv, const float* bv,
                                               short* xprep,
                                               short* wp1, short* wp2, short* w8p,
                                               short* wall, float* ball,
                                               float* st, float* pl) {
    int blk = blockIdx.x, t = threadIdx.x;
    if (blk < 512) prep_body<8>(x, xprep, blk, t);
    else weights_body(w1, w2, w8, wq, bq, wk, bk, wv, bv,
                      wp1, wp2, w8p, wall, ball, st, pl, blk - 512, t);
}

// PAM-merge + prep: sa = feat1 + g*(sum_jc PO)/PL -> bf16 [b][2][h][w][ci32]
__device__ __forceinline__ void pamprep_body(const short* __restrict__ po,
                                             const float* __restrict__ pl_acc,
                                             const float* __restrict__ feat1,
                                             const float* __restrict__ gp,
                                             short* __restrict__ out, int blk, int t) {
    __shared__ short tl[4][64][34];
    int hq = blk & 15;
    int ch = (blk >> 4) & 1;
    int b  = blk >> 5;
    float g = gp[0];

    #pragma unroll
    for (int i = 0; i < 32; ++i) {
        int idx = i * 256 + t;
        int w = idx & 63, hh = (idx >> 6) & 3, ci = idx >> 8;
        int pix = (hq * 4 + hh) * 64 + w;
        size_t o = ((size_t)(b * 64 + ch * 32 + ci)) * NPIX + pix;
        float s = bs2f((unsigned short)po[o])
                + bs2f((unsigned short)po[o + 1048576])
                + bs2f((unsigned short)po[o + 2097152])
                + bs2f((unsigned short)po[o + 3145728]);
        float v = feat1[o] + g * s / pl_acc[b * NPIX + pix];
        tl[hh][w][ci] = f2bs(v);
    }
    __syncthreads();
    unsigned* outu = (unsigned*)(out + (((size_t)(b * 2 + ch)) * NPIX + hq * 4 * 64) * 32);
    #pragma unroll
    for (int i = 0; i < 16; ++i) {
        int j = i * 256 + t;
        int cip = j & 15, w = (j >> 4) & 63, hh = j >> 10;
        unsigned v = *(unsigned*)&tl[hh][w][2 * cip];
        outu[(size_t)(hh * 64 + w) * 16 + cip] = v;
    }
}

// fused prep<2>(scfeat) + pamprep
__global__ __launch_bounds__(256) void k_preppam(const float* __restrict__ scfeat,
                                                 short* __restrict__ sprep_sc,
                                                 const short* __restrict__ po,
                                                 const float* __restrict__ pl_acc,
                                                 const float* __restrict__ feat1,
                                                 const float* __restrict__ gp,
                                                 short* __restrict__ saprep) {
    int blk = blockIdx.x, t = threadIdx.x;
    if (blk < 128) prep_body<2>(scfeat, sprep_sc, blk, t);
    else pamprep_body(po, pl_acc, feat1, gp, saprep, blk - 128, t);
}

// 3x3 SAME conv via MFMA, K-split body: blk in [0,512): ks=blk>>8, b, h
template<int NCH>
__device__ __forceinline__ void conv_body(const short* __restrict__ xprep,
                                          const short* __restrict__ wp,
                                          float* __restrict__ y0,
                                          float* __restrict__ y1,
                                          int blk, int t) {
    __shared__ __align__(16) short xl[3][66][32];
    int lane = t & 63, wv = t >> 6;
    int ks = blk >> 8;
    int b = (blk >> 6) & 3, h = blk & 63;
    int g = lane >> 4, n16 = lane & 15;
    constexpr int NH = NCH / 2;
    int c0 = ks * NH;

    if (t < 24) {
        int r = t >> 3, cc = ((t >> 2) & 1) ? 65 : 0, u = t & 3;
        bf16x8 z = {};
        *(bf16x8*)&xl[r][cc][u * 8] = z;
    }

    f32x4 acc[4];
    #pragma unroll
    for (int i = 0; i < 4; ++i) acc[i] = (f32x4){0.f, 0.f, 0.f, 0.f};

    int sw = t >> 2, su = t & 3;
    int spu = su ^ swz(sw + 1);

    for (int ch = c0; ch < c0 + NH; ++ch) {
        __syncthreads();
        #pragma unroll
        for (int r = 0; r < 3; ++r) {
            int hh = h + r - 1;
            bf16x8 v = {};
            if (hh >= 0 && hh < 64)
                v = *(const bf16x8*)(xprep + (((size_t)(b * NCH + ch)) * 64 + hh) * 64 * 32 + sw * 32 + su * 8);
            *(bf16x8*)&xl[r][sw + 1][spu * 8] = v;
        }
        __syncthreads();

        const short* wbase = wp + ((size_t)(ch * 9)) * 64 * 32;
        #pragma unroll
        for (int tap = 0; tap < 9; ++tap) {
            int kr = tap / 3, kc = tap % 3;
            bf16x8 a = *(const bf16x8*)(wbase + ((size_t)(tap * 64 + wv * 16 + n16)) * 32 + g * 8);
            #pragma unroll
            for (int nt = 0; nt < 4; ++nt) {
                int wpix = nt * 16 + n16 + kc;
                int pu = g ^ swz(wpix);
                bf16x8 bx = *(const bf16x8*)&xl[kr][wpix][pu * 8];
                acc[nt] = __builtin_amdgcn_mfma_f32_16x16x32_bf16(a, bx, acc[nt], 0, 0, 0);
            }
        }
    }

    float* y = ks ? y1 : y0;
    #pragma unroll
    for (int nt = 0; nt < 4; ++nt) {
        #pragma unroll
        for (int r = 0; r < 4; ++r) {
            int co = wv * 16 + g * 4 + r;
            y[((size_t)(b * CI + co)) * NPIX + h * 64 + nt * 16 + n16] = acc[nt][r];
        }
    }
}

template<int NCH>
__global__ __launch_bounds__(256) void k_convmfma(const short* __restrict__ xprep,
                                                  const short* __restrict__ wp,
                                                  float* __restrict__ y0,
                                                  float* __restrict__ y1) {
    conv_body<NCH>(xprep, wp, y0, y1, blockIdx.x, threadIdx.x);
}

// both conv2's in one dispatch
__global__ __launch_bounds__(256) void k_conv2x(const short* __restrict__ inA,
                                                const short* __restrict__ inB,
                                                const short* __restrict__ wp,
                                                float* a0, float* a1,
                                                float* b0, float* b1) {
    int blk = blockIdx.x;
    int w = blk >> 9;
    conv_body<2>(w ? inB : inA, wp, w ? b0 : a0, w ? b1 : a1, blk & 511, threadIdx.x);
}

// BN stats from two conv partials
__device__ __forceinline__ void bnstats_body(const float* __restrict__ y0,
                                             const float* __restrict__ y1,
                                             float* stats, int blk, int t) {
    int c = blk >> 2, b = blk & 3;
    size_t base = ((size_t)(b * 64 + c)) * NPIX;
    float s = 0.f, sq = 0.f;
    for (int i = t; i < NPIX; i += 256) {
        float v = y0[base + i] + y1[base + i];
        s += v; sq += v * v;
    }
    __shared__ float rs[8];
    for (int o = 32; o; o >>= 1) { s += __shfl_down(s, o); sq += __shfl_down(sq, o); }
    if ((t & 63) == 0) { rs[t >> 6] = s; rs[4 + (t >> 6)] = sq; }
    __syncthreads();
    if (t == 0) {
        atomicAdd(&stats[c], rs[0] + rs[1] + rs[2] + rs[3]);
        atomicAdd(&stats[64 + c], rs[4] + rs[5] + rs[6] + rs[7]);
    }
}

__global__ __launch_bounds__(256) void k_bnstats(const float* y0, const float* y1, float* stats) {
    bnstats_body(y0, y1, stats, blockIdx.x, threadIdx.x);
}
__global__ __launch_bounds__(256) void k_bnstats2x(const float* a0, const float* a1,
                                                   const float* b0, const float* b1,
                                                   float* sta, float* stb) {
    int blk = blockIdx.x;
    int w = blk >> 8;
    bnstats_body(w ? b0 : a0, w ? b1 : a1, w ? stb : sta, blk & 255, threadIdx.x);
}

__device__ __forceinline__ void bnapply_body(const float* y0, const float* y1,
                                             const float* stats, const float* g,
                                             const float* bta, float* out, int i) {
    int c = (i >> 12) & 63;
    float mean = stats[c] * (1.f / 16384.f);
    float var = stats[64 + c] * (1.f / 16384.f) - mean * mean;
    float rs = rsqrtf(var + 1e-5f);
    float v = (y0[i] + y1[i] - mean) * rs * g[c] + bta[c];
    out[i] = v > 0.f ? v : 0.f;
}

__global__ __launch_bounds__(256) void k_bnapply2(const float* y0, const float* y1,
                                                  const float* stats, const float* g,
                                                  const float* bta, float* out) {
    bnapply_body(y0, y1, stats, g, bta, out, blockIdx.x * 256 + threadIdx.x);
}
__global__ __launch_bounds__(256) void k_bnapply2x(const float* a0, const float* a1,
                                                   const float* b0, const float* b1,
                                                   const float* sta, const float* stb,
                                                   const float* g, const float* bta,
                                                   float* oa, float* ob) {
    int blk = blockIdx.x;
    int w = blk >> 12;
    int i = (blk & 4095) * 256 + threadIdx.x;
    bnapply_body(w ? b0 : a0, w ? b1 : a1, w ? stb : sta, g, bta, w ? ob : oa, i);
}

// q/k/v via MFMA body (256 virtual blocks)
__device__ __forceinline__ void qkv_body(const float* __restrict__ feat1,
                                         const short* __restrict__ wall,
                                         const float* __restrict__ ball,
                                         short* __restrict__ q,
                                         short* __restrict__ k,
                                         short* __restrict__ v, int blk, int t) {
    __shared__ __align__(16) short fl[64][64];
    int lane = t & 63, wv = t >> 6;
    int h = blk & 63, b = blk >> 6;
    int n16 = lane & 15, g = lane >> 4;

    {
        int n = t & 63, ug2 = t >> 6;
        const float* fp = feat1 + ((size_t)b * CI) * NPIX + h * 64 + n;
        #pragma unroll
        for (int uu = 0; uu < 2; ++uu) {
            int u = ug2 + uu * 4;
            int ci0 = u * 8;
            short tmp[8];
            #pragma unroll
            for (int j = 0; j < 8; ++j) tmp[j] = f2bs(fp[(size_t)(ci0 + j) * NPIX]);
            int phys = u ^ (n & 7);
            *(bf16x8*)&fl[n][phys * 8] = *(bf16x8*)tmp;
        }
    }
    __syncthreads();

    f32x4 acc[4];
    #pragma unroll
    for (int i = 0; i < 4; ++i) acc[i] = (f32x4){0.f, 0.f, 0.f, 0.f};
    f32x4 acc4 = (f32x4){0.f, 0.f, 0.f, 0.f};

    #pragma unroll
    for (int kc = 0; kc < 2; ++kc) {
        bf16x8 a = *(const bf16x8*)&wall[(size_t)(wv * 16 + n16) * 64 + kc * 32 + g * 8];
        bf16x8 a4 = *(const bf16x8*)&wall[(size_t)(64 + n16) * 64 + kc * 32 + g * 8];
        #pragma unroll
        for (int nt = 0; nt < 4; ++nt) {
            int n = nt * 16 + n16;
            int phys = (kc * 4 + g) ^ (n & 7);
            bf16x8 bx = *(const bf16x8*)&fl[n][phys * 8];
            acc[nt] = __builtin_amdgcn_mfma_f32_16x16x32_bf16(a, bx, acc[nt], 0, 0, 0);
            if (nt == wv) acc4 = __builtin_amdgcn_mfma_f32_16x16x32_bf16(a4, bx, acc4, 0, 0, 0);
        }
    }

    #pragma unroll
    for (int nt = 0; nt < 4; ++nt) {
        int pix = h * 64 + nt * 16 + n16;
        #pragma unroll
        for (int r = 0; r < 4; ++r) {
            int co = wv * 16 + g * 4 + r;
            short val = f2bs(acc[nt][r] + ball[co]);
            if (co < 8)       q[((size_t)(b * 8 + co)) * NPIX + pix] = val;
            else if (co < 16) k[((size_t)(b * 8 + co - 8)) * NPIX + pix] = val;
            else              v[((size_t)(b * 64 + co - 16)) * NPIX + pix] = val;
        }
    }
    {
        int pix = h * 64 + wv * 16 + n16;
        #pragma unroll
        for (int r = 0; r < 4; ++r) {
            int co = 64 + g * 4 + r;
            v[((size_t)(b * 64 + co - 16)) * NPIX + pix] = f2bs(acc4[r] + ball[co]);
        }
    }
}

// CAM gram partials body (256 virtual blocks)
__device__ __forceinline__ void gram_body(const float* __restrict__ f,
                                          float* __restrict__ gp, int blk, int t) {
    __shared__ __align__(16) float fl[64 * 68];
    int b = blk >> 6, nc = blk & 63;
    int n0 = nc * 64;
    int c = t & 63, dg = t >> 6;
    float acc[16];
    #pragma unroll
    for (int i = 0; i < 16; ++i) acc[i] = 0.f;
    for (int idx = t; idx < 4096; idx += 256) {
        int cc = idx >> 6, nn = idx & 63;
        fl[nn * 68 + cc] = f[((size_t)b * 64 + cc) * NPIX + n0 + nn];
    }
    __syncthreads();
    for (int nn = 0; nn < 64; ++nn) {
        float fc = fl[nn * 68 + c];
        const float4* fd = (const float4*)(fl + nn * 68 + dg * 16);
        #pragma unroll
        for (int k4 = 0; k4 < 4; ++k4) {
            float4 vv = fd[k4];
            acc[k4 * 4 + 0] += fc * vv.x;
            acc[k4 * 4 + 1] += fc * vv.y;
            acc[k4 * 4 + 2] += fc * vv.z;
            acc[k4 * 4 + 3] += fc * vv.w;
        }
    }
    float* dst = gp + (size_t)nc * 16384 + ((size_t)b * 64 + c) * 64 + dg * 16;
    #pragma unroll
    for (int kk = 0; kk < 16; ++kk) dst[kk] = acc[kk];
}

// fused qkv + gram (both read feat1 only)
__global__ __launch_bounds__(256) void k_qkvgram(const float* __restrict__ feat1,
                                                 const short* __restrict__ wall,
                                                 const float* __restrict__ ball,
                                                 short* q, short* k, short* v,
                                                 float* gp) {
    int blk = blockIdx.x, t = threadIdx.x;
    if (blk < 256) qkv_body(feat1, wall, ball, q, k, v, blk, t);
    else gram_body(feat1, gp, blk - 256, t);
}

// PAM partial pass (round-12 proven version): 128-wide j rounds, swapped QK,
// direct-global V (av[4]), kl[128][16], pl[64][136]. VGPR ~52.
__global__ __launch_bounds__(256) void k_pampart(const short* __restrict__ q,
                                                 const short* __restrict__ k,
                                                 const short* __restrict__ v,
                                                 short* __restrict__ po,
                                                 float* __restrict__ pl_acc) {
    __shared__ __align__(16) short kl[128][16];  // [j][d]; d 8..15 zeroed once
    __shared__ __align__(16) short pl[64][136];  // [i][j] bf16, padded

    int t = threadIdx.x;
    int lane = t & 63, w = t >> 6;
    int blk = blockIdx.x;
    int jc = blk >> 8, b = (blk >> 6) & 3, ic = blk & 63;
    int i0 = ic * 64;
    int n16 = lane & 15, g = lane >> 4;

    const short* qb = q + (size_t)b * 8 * NPIX;
    const short* kb = k + (size_t)b * 8 * NPIX;
    const short* vb = v + (size_t)b * 64 * NPIX;

    #pragma unroll
    for (int i = 0; i < 2; ++i) {
        int idx = i * 256 + t;
        int jj = idx & 127, dz = 8 + ((idx >> 7) << 1);
        *(unsigned*)&kl[jj][dz] = 0u;
    }

    // aq as B-operand: lane<16 holds q[d=e][i0+w*16+lane]
    bf16x8 aq = {};
    if (lane < 16) {
        int irow = i0 + w * 16 + lane;
        #pragma unroll
        for (int e = 0; e < 8; ++e) aq[e] = qb[(size_t)e * NPIX + irow];
    }

    f32x4 acc[4];
    #pragma unroll
    for (int i = 0; i < 4; ++i) acc[i] = (f32x4){0.f, 0.f, 0.f, 0.f};
    float lacc = 0.f;
    const f32x4 zz = {0.f, 0.f, 0.f, 0.f};

    for (int ro = 0; ro < 8; ++ro) {
        int j0 = jc * 1024 + ro * 128;
        // stage K (128j x 8d)
        #pragma unroll
        for (int i = 0; i < 2; ++i) {
            int idx = i * 256 + t;
            int jj = idx & 127, dp2 = idx >> 7;
            unsigned lo = (unsigned short)kb[(size_t)(dp2 * 2) * NPIX + j0 + jj];
            unsigned hi = (unsigned short)kb[(size_t)(dp2 * 2 + 1) * NPIX + j0 + jj];
            *(unsigned*)&kl[jj][dp2 * 2] = lo | (hi << 16);
        }
        // V fragments direct from global (issue early; consumed after next barrier)
        bf16x8 av[4];
        #pragma unroll
        for (int ks = 0; ks < 4; ++ks)
            av[ks] = *(const bf16x8*)&vb[(size_t)(w * 16 + n16) * NPIX + j0 + ks * 32 + g * 8];
        __syncthreads();

        // swapped QK: mfma(K,Q) -> D[j][i]; lane holds 4 consecutive j at col i=n16
        #pragma unroll
        for (int jsub = 0; jsub < 8; ++jsub) {
            bf16x8 bk = {};
            if (lane < 32)
                bk = *(const bf16x8*)&kl[jsub * 16 + n16][g * 8];
            f32x4 s = __builtin_amdgcn_mfma_f32_16x16x32_bf16(bk, aq, zz, 0, 0, 0);
            float e0 = exp2f(s[0]), e1 = exp2f(s[1]), e2 = exp2f(s[2]), e3 = exp2f(s[3]);
            lacc += (e0 + e1) + (e2 + e3);
            bf16x4 pk = { f2bs(e0), f2bs(e1), f2bs(e2), f2bs(e3) };
            *(bf16x4*)&pl[w * 16 + n16][jsub * 16 + g * 4] = pk;
        }
        __syncthreads();

        // O^T += V * P^T (16 MFMA)
        #pragma unroll
        for (int isub = 0; isub < 4; ++isub) {
            #pragma unroll
            for (int ks = 0; ks < 4; ++ks) {
                bf16x8 bp = *(const bf16x8*)&pl[isub * 16 + n16][ks * 32 + g * 8];
                acc[isub] = __builtin_amdgcn_mfma_f32_16x16x32_bf16(av[ks], bp, acc[isub], 0, 0, 0);
            }
        }
        __syncthreads();
    }

    // l reduce: lanes {n16, n16+16, n16+32, n16+48} share row i0+w*16+n16
    {
        float lv = lacc;
        lv += __shfl_xor(lv, 16);
        lv += __shfl_xor(lv, 32);
        if (lane < 16)
            atomicAdd(&pl_acc[b * NPIX + i0 + w * 16 + lane], lv);
    }

    #pragma unroll
    for (int isub = 0; isub < 4; ++isub) {
        #pragma unroll
        for (int r = 0; r < 4; ++r) {
            int c = w * 16 + g * 4 + r;
            size_t o = ((size_t)((jc * BB + b) * 64 + c)) * NPIX + i0 + isub * 16 + n16;
            po[o] = f2bs(acc[isub][r]);
        }
    }
}

// fused gram-reduce + channel softmax
__global__ void k_camsm2(const float* __restrict__ gp, float* __restrict__ cattn) {
    int row = blockIdx.x;
    int d = threadIdx.x;
    float v = 0.f;
    #pragma unroll 8
    for (int p = 0; p < 64; ++p) v += gp[(size_t)p * 16384 + row * 64 + d];
    float mn = v;
    for (int s = 32; s; s >>= 1) mn = fminf(mn, __shfl_xor(mn, s));
    float e = exp2f((mn - v) * LOG2E);
    float sum = e;
    for (int s = 32; s; s >>= 1) sum += __shfl_xor(sum, s);
    cattn[(size_t)row * 64 + d] = e / sum;
}

// sc_feat = gamma_cam * (cattn @ f) + feat1
__global__ __launch_bounds__(256) void k_cam(const float* __restrict__ cattn,
                                             const float* __restrict__ f,
                                             const float* __restrict__ gcp,
                                             float* __restrict__ sc) {
    __shared__ __align__(16) float Al[64 * 68];
    __shared__ float fl[64 * 64];
    int blk = blockIdx.x;
    int b = blk >> 6, nc = blk & 63;
    int n0 = nc * 64;
    int t = threadIdx.x;
    int nl = t & 63, cg = t >> 6;
    for (int idx = t; idx < 4096; idx += 256) {
        int cc = idx >> 6, dd = idx & 63;
        Al[dd * 68 + cc] = cattn[((size_t)b * 64 + cc) * 64 + dd];
    }
    for (int idx = t; idx < 4096; idx += 256) {
        int dd = idx >> 6, nn = idx & 63;
        fl[dd * 64 + nn] = f[((size_t)b * 64 + dd) * NPIX + n0 + nn];
    }
    __syncthreads();
    float acc[16];
    #pragma unroll
    for (int i = 0; i < 16; ++i) acc[i] = 0.f;
    for (int d = 0; d < 64; ++d) {
        float fv = fl[d * 64 + nl];
        const float4* A4 = (const float4*)(Al + d * 68 + cg * 16);
        #pragma unroll
        for (int k4 = 0; k4 < 4; ++k4) {
            float4 a = A4[k4];
            acc[k4 * 4 + 0] += a.x * fv;
            acc[k4 * 4 + 1] += a.y * fv;
            acc[k4 * 4 + 2] += a.z * fv;
            acc[k4 * 4 + 3] += a.w * fv;
        }
    }
    float g = gcp[0];
    #pragma unroll
    for (int kk = 0; kk < 16; ++kk) {
        int c = cg * 16 + kk;
        size_t o = ((size_t)b * 64 + c) * NPIX + n0 + nl;
        sc[o] = g * acc[kk] + f[o];
    }
}

// out = w8 @ (sa_conv + sc_conv) + b8 via MFMA (1x1, 64 -> 256)
__global__ __launch_bounds__(256) void k_finalmfma(const float* __restrict__ sa,
                                                   const float* __restrict__ sc,
                                                   const short* __restrict__ w8p,
                                                   const float* __restrict__ b8,
                                                   float* __restrict__ out) {
    __shared__ __align__(16) short fl[64][64];
    int t = threadIdx.x;
    int lane = t & 63, wv = t >> 6;
    int blk = blockIdx.x;
    int h = blk & 63, b = (blk >> 6) & 3, cq = blk >> 8;
    int n16 = lane & 15, g = lane >> 4;

    {
        int n = t & 63, ug2 = t >> 6;
        const float* sap = sa + ((size_t)b * CI) * NPIX + h * 64 + n;
        const float* scp = sc + ((size_t)b * CI) * NPIX + h * 64 + n;
        #pragma unroll
        for (int uu = 0; uu < 2; ++uu) {
            int u = ug2 + uu * 4;
            int ci0 = u * 8;
            short tmp[8];
            #pragma unroll
            for (int j = 0; j < 8; ++j) {
                size_t o = (size_t)(ci0 + j) * NPIX;
                tmp[j] = f2bs(sap[o] + scp[o]);
            }
            int phys = u ^ (n & 7);
            *(bf16x8*)&fl[n][phys * 8] = *(bf16x8*)tmp;
        }
    }
    __syncthreads();

    f32x4 acc[4];
    #pragma unroll
    for (int i = 0; i < 4; ++i) acc[i] = (f32x4){0.f, 0.f, 0.f, 0.f};
    int cobase = cq * 64 + wv * 16;

    #pragma unroll
    for (int kc = 0; kc < 2; ++kc) {
        bf16x8 a = *(const bf16x8*)&w8p[(size_t)(cobase + n16) * 64 + kc * 32 + g * 8];
        #pragma unroll
        for (int nt = 0; nt < 4; ++nt) {
            int n = nt * 16 + n16;
            int phys = (kc * 4 + g) ^ (n & 7);
            bf16x8 bx = *(const bf16x8*)&fl[n][phys * 8];
            acc[nt] = __builtin_amdgcn_mfma_f32_16x16x32_bf16(a, bx, acc[nt], 0, 0, 0);
        }
    }

    #pragma unroll
    for (int nt = 0; nt < 4; ++nt) {
        #pragma unroll
        for (int r = 0; r < 4; ++r) {
            int co = cobase + g * 4 + r;
            out[((size_t)(b * COUT + co)) * NPIX + h * 64 + nt * 16 + n16] = acc[nt][r] + b8[co];
        }
    }
}

// ---------------- launcher ----------------
extern "C" void kernel_launch(void* const* d_in, const int* in_sizes, int n_in,
                              void* d_out, int out_size, void* d_ws, size_t ws_size,
                              hipStream_t stream) {
    (void)in_sizes; (void)n_in; (void)out_size; (void)ws_size;
    const float* x    = (const float*)d_in[0];
    const float* w1   = (const float*)d_in[1];
    const float* bng  = (const float*)d_in[2];
    const float* bnb  = (const float*)d_in[3];
    const float* wq   = (const float*)d_in[4];
    const float* bq   = (const float*)d_in[5];
    const float* wk   = (const float*)d_in[6];
    const float* bk   = (const float*)d_in[7];
    const float* wv   = (const float*)d_in[8];
    const float* bv   = (const float*)d_in[9];
    const float* gpam = (const float*)d_in[10];
    const float* gcam = (const float*)d_in[11];
    const float* w2   = (const float*)d_in[12];
    const float* w8   = (const float*)d_in[13];
    const float* b8   = (const float*)d_in[14];
    float* out = (float*)d_out;

    char* WB = (char*)d_ws;
    float* fC1P0   = (float*)(WB + B_Y1V);            // conv1 p0
    float* fC1P1   = (float*)(WB + B_SACONV);         // conv1 p1
    float* fGP     = (float*)(WB + B_SACONV);         // gram partials (4MB, after C1P1 dies)
    short* fV      = (short*)(WB + B_Y1V);            // V bf16 (2MB)
    short* fSPREPSC= (short*)(WB + B_Y1V + 0x200000); // sc-prep bf16 (2MB)
    short* fSAPREP = (short*)(WB + B_Y1V);            // sa-prep bf16 (2MB, after V dies)
    float* fFEAT1  = (float*)(WB + B_FEAT1);
    short* fXPREP  = (short*)(WB + B_SA);             // 8MB spanning SA+Y2
    float* fSCFEAT = (float*)(WB + B_SA);
    float* fC2B1   = (float*)(WB + B_SA);             // conv2b p1; SCCONV in-place
    short* fPO     = (short*)(WB + B_Y2);             // 8MB spanning Y2+SACONV
    float* fC2A0   = (float*)(WB + B_Y2);             // conv2a p0
    float* fC2B0   = (float*)(WB + B_FEAT1);          // conv2b p0 (feat1 dead)
    float* fC2A1   = (float*)(WB + B_SACONV);         // conv2a p1; SACONV in-place
    short* fQ      = (short*)(WB + B_Q);
    short* fK      = (short*)(WB + B_K);
    float* fST     = (float*)(WB + B_ST);
    float* fST2a   = fST + 128;
    float* fST2b   = fST + 256;
    float* fCATT   = (float*)(WB + B_CATT);
    short* fWP1    = (short*)(WB + B_WP1);
    short* fWP2    = (short*)(WB + B_WP2);
    float* fPL     = (float*)(WB + B_PL);
    short* fW8P    = (short*)(WB + B_W8P);
    short* fWQKV   = (short*)(WB + B_WQKV);
    float* fBALL   = (float*)(WB + B_BALL);

    k_prepw<<<1382, 256, 0, stream>>>(x, w1, w2, w8, wq, bq, wk, bk, wv, bv,
                                      fXPREP, fWP1, fWP2, fW8P, fWQKV, fBALL, fST, fPL);

    k_convmfma<8><<<512, 256, 0, stream>>>(fXPREP, fWP1, fC1P0, fC1P1);
    k_bnstats<<<256, 256, 0, stream>>>(fC1P0, fC1P1, fST);
    k_bnapply2<<<4096, 256, 0, stream>>>(fC1P0, fC1P1, fST, bng, bnb, fFEAT1);

    k_qkvgram<<<512, 256, 0, stream>>>(fFEAT1, fWQKV, fBALL, fQ, fK, fV, fGP);
    k_camsm2<<<256, 64, 0, stream>>>(fGP, fCATT);        // GP consumed before PO clobbers it

    k_pampart<<<1024, 256, 0, stream>>>(fQ, fK, fV, fPO, fPL);
    k_cam<<<256, 256, 0, stream>>>(fCATT, fFEAT1, gcam, fSCFEAT);
    k_preppam<<<256, 256, 0, stream>>>(fSCFEAT, fSPREPSC, fPO, fPL, fFEAT1, gpam, fSAPREP);

    k_conv2x<<<1024, 256, 0, stream>>>(fSAPREP, fSPREPSC, fWP2, fC2A0, fC2A1, fC2B0, fC2B1);
    k_bnstats2x<<<512, 256, 0, stream>>>(fC2A0, fC2A1, fC2B0, fC2B1, fST2a, fST2b);
    k_bnapply2x<<<8192, 256, 0, stream>>>(fC2A0, fC2A1, fC2B0, fC2B1, fST2a, fST2b,
                                          bng, bnb, fC2A1, fC2B1);

    k_finalmfma<<<1024, 256, 0, stream>>>(fC2A1, fC2B1, fW8P, b8, out);
}

// Round 15
// 136.368 us; speedup vs baseline: 1.0966x; 1.0054x over previous
//
#include <hip/hip_runtime.h>
#include <hip/hip_bf16.h>

// ---------------- problem constants ----------------
#define BB   4
#define CIN  256
#define CI   64
#define COUT 256
#define NPIX 4096          // 64*64
#define LOG2E 1.44269504088896340736f

// ---------------- ws layout (BYTE offsets) ----------------
#define B_Y1V    0x0000000u  // 4MB: conv1-p0 f32 -> {V bf16 @0, SPREP_SC bf16 @2MB} -> SAPREP bf16 @0
#define B_FEAT1  0x0400000u  // 4MB f32 feat1; later conv2b-p0
#define B_SA     0x0800000u  // 4MB: xprep head; SCFEAT f32; conv2b-p1 (in-place SCCONV)
#define B_Y2     0x0C00000u  // 4MB: xprep tail; PO head; conv2a-p0
#define B_SACONV 0x1000000u  // 4MB: conv1-p1; GP f32; PO tail; conv2a-p1 (in-place SACONV)
#define B_Q      0x1400000u  // 256KB bf16[131072] (q, LOG2E-prescaled)
#define B_K      0x1480000u  // 256KB bf16
#define B_ST     0x15A0000u  // 1.5KB f32[384]
#define B_CATT   0x15B1000u  // 64KB
#define B_WP1    0x15C1000u  // 288KB bf16[147456]
#define B_WP2    0x1610000u  // 72KB  bf16[36864]
#define B_PL     0x1630000u  // 64KB f32[16384] partial-l accumulator
#define B_W8P    0x1640000u  // 32KB bf16[16384]
#define B_WQKV   0x1648000u  // 10KB bf16[5120]
#define B_BALL   0x164B000u  // 320B f32[80]

typedef __attribute__((ext_vector_type(8))) short bf16x8;
typedef __attribute__((ext_vector_type(4))) short bf16x4;
typedef __attribute__((ext_vector_type(4))) float f32x4;

__device__ __forceinline__ short f2bs(float f) {
    union { float f; unsigned u; } c; c.f = f;
    unsigned r = c.u + 0x7FFFu + ((c.u >> 16) & 1u);
    return (short)(r >> 16);
}
__device__ __forceinline__ float bs2f(unsigned short s) {
    union { unsigned u; float f; } c; c.u = ((unsigned)s) << 16;
    return c.f;
}
__device__ __forceinline__ int swz(int wp) { return (wp ^ (wp >> 2)) & 3; }

// ---------------- bodies ----------------

// weight-prep + zeroing (870 virtual blocks)
__device__ __forceinline__ void weights_body(const float* __restrict__ w1,
                                             const float* __restrict__ w2,
                                             const float* __restrict__ w8,
                                             const float* wq, const float* bq,
                                             const float* wk, const float* bk,
                                             const float* wv, const float* bv,
                                             short* wp1, short* wp2, short* w8p,
                                             short* wall, float* ball,
                                             float* st, float* pl, int blk, int t) {
    if (blk < 576) {
        int idx = blk * 256 + t;
        if (idx < 147456) {
            int cil = idx & 31, co = (idx >> 5) & 63;
            int rest = idx >> 11, tap = rest % 9, ch = rest / 9;
            wp1[idx] = f2bs(w1[co * CIN * 9 + (ch * 32 + cil) * 9 + tap]);
        }
    } else if (blk < 720) {
        int idx = (blk - 576) * 256 + t;
        if (idx < 36864) {
            int cil = idx & 31, co = (idx >> 5) & 63;
            int rest = idx >> 11, tap = rest % 9, ch = rest / 9;
            wp2[idx] = f2bs(w2[co * CI * 9 + (ch * 32 + cil) * 9 + tap]);
        }
    } else if (blk < 784) {
        int idx = (blk - 720) * 256 + t;
        w8p[idx] = f2bs(w8[idx]);
    } else if (blk < 804) {
        int idx = (blk - 784) * 256 + t;
        if (idx < 5120) {
            int co = idx >> 6, ci = idx & 63;
            float v;
            if (co < 8)       v = wq[co * 64 + ci] * LOG2E;
            else if (co < 16) v = wk[(co - 8) * 64 + ci];
            else              v = wv[(co - 16) * 64 + ci];
            wall[idx] = f2bs(v);
        }
        if (idx < 80) {
            float v;
            if (idx < 8)       v = bq[idx] * LOG2E;
            else if (idx < 16) v = bk[idx - 8];
            else               v = bv[idx - 16];
            ball[idx] = v;
        }
    } else if (blk < 806) {
        int idx = (blk - 804) * 256 + t;
        if (idx < 384) st[idx] = 0.f;
    } else {
        int idx = (blk - 806) * 256 + t;
        pl[idx] = 0.f;
    }
}

// transpose f32 [b][NCH*32 ci][4096] -> bf16 [b][NCH][h][w][ci32]
template<int NCH>
__device__ __forceinline__ void prep_body(const float* __restrict__ in,
                                          short* __restrict__ out, int blk, int t) {
    __shared__ short tl[4][64][34];
    int hq = blk & 15;
    int ch = (blk >> 4) % NCH;
    int b  = blk / (16 * NCH);
    const int CINT = NCH * 32;

    #pragma unroll
    for (int i = 0; i < 32; ++i) {
        int idx = i * 256 + t;
        int w = idx & 63, hh = (idx >> 6) & 3, ci = idx >> 8;
        float v = in[((size_t)(b * CINT + ch * 32 + ci)) * NPIX + (hq * 4 + hh) * 64 + w];
        tl[hh][w][ci] = f2bs(v);
    }
    __syncthreads();
    unsigned* outu = (unsigned*)(out + (((size_t)(b * NCH + ch)) * NPIX + hq * 4 * 64) * 32);
    #pragma unroll
    for (int i = 0; i < 16; ++i) {
        int j = i * 256 + t;
        int cip = j & 15, w = (j >> 4) & 63, hh = j >> 10;
        unsigned v = *(unsigned*)&tl[hh][w][2 * cip];
        outu[(size_t)(hh * 64 + w) * 16 + cip] = v;
    }
}

// fused weights + prep<8>
__global__ __launch_bounds__(256) void k_prepw(const float* __restrict__ x,
                                               const float* w1, const float* w2, const float* w8,
                                               const float* wq, const float* bq,
                                               const float* wk, const float* bk,
                                               const float* wv, const float* bv,
                                               short* xprep,
                                               short* wp1, short* wp2, short* w8p,
                                               short* wall, float* ball,
                                               float* st, float* pl) {
    int blk = blockIdx.x, t = threadIdx.x;
    if (blk < 512) prep_body<8>(x, xprep, blk, t);
    else weights_body(w1, w2, w8, wq, bq, wk, bk, wv, bv,
                      wp1, wp2, w8p, wall, ball, st, pl, blk - 512, t);
}

// PAM-merge + prep: sa = feat1 + g*(sum_jc PO)/PL -> bf16 [b][2][h][w][ci32]
__device__ __forceinline__ void pamprep_body(const short* __restrict__ po,
                                             const float* __restrict__ pl_acc,
                                             const float* __restrict__ feat1,
                                             const float* __restrict__ gp,
                                             short* __restrict__ out, int blk, int t) {
    __shared__ short tl[4][64][34];
    int hq = blk & 15;
    int ch = (blk >> 4) & 1;
    int b  = blk >> 5;
    float g = gp[0];

    #pragma unroll
    for (int i = 0; i < 32; ++i) {
        int idx = i * 256 + t;
        int w = idx & 63, hh = (idx >> 6) & 3, ci = idx >> 8;
        int pix = (hq * 4 + hh) * 64 + w;
        size_t o = ((size_t)(b * 64 + ch * 32 + ci)) * NPIX + pix;
        float s = bs2f((unsigned short)po[o])
                + bs2f((unsigned short)po[o + 1048576])
                + bs2f((unsigned short)po[o + 2097152])
                + bs2f((unsigned short)po[o + 3145728]);
        float v = feat1[o] + g * s / pl_acc[b * NPIX + pix];
        tl[hh][w][ci] = f2bs(v);
    }
    __syncthreads();
    unsigned* outu = (unsigned*)(out + (((size_t)(b * 2 + ch)) * NPIX + hq * 4 * 64) * 32);
    #pragma unroll
    for (int i = 0; i < 16; ++i) {
        int j = i * 256 + t;
        int cip = j & 15, w = (j >> 4) & 63, hh = j >> 10;
        unsigned v = *(unsigned*)&tl[hh][w][2 * cip];
        outu[(size_t)(hh * 64 + w) * 16 + cip] = v;
    }
}

// fused prep<2>(scfeat) + pamprep
__global__ __launch_bounds__(256) void k_preppam(const float* __restrict__ scfeat,
                                                 short* __restrict__ sprep_sc,
                                                 const short* __restrict__ po,
                                                 const float* __restrict__ pl_acc,
                                                 const float* __restrict__ feat1,
                                                 const float* __restrict__ gp,
                                                 short* __restrict__ saprep) {
    int blk = blockIdx.x, t = threadIdx.x;
    if (blk < 128) prep_body<2>(scfeat, sprep_sc, blk, t);
    else pamprep_body(po, pl_acc, feat1, gp, saprep, blk - 128, t);
}

// 3x3 SAME conv via MFMA, K-split body: blk in [0,512): ks=blk>>8, b, h
template<int NCH>
__device__ __forceinline__ void conv_body(const short* __restrict__ xprep,
                                          const short* __restrict__ wp,
                                          float* __restrict__ y0,
                                          float* __restrict__ y1,
                                          int blk, int t) {
    __shared__ __align__(16) short xl[3][66][32];
    int lane = t & 63, wv = t >> 6;
    int ks = blk >> 8;
    int b = (blk >> 6) & 3, h = blk & 63;
    int g = lane >> 4, n16 = lane & 15;
    constexpr int NH = NCH / 2;
    int c0 = ks * NH;

    if (t < 24) {
        int r = t >> 3, cc = ((t >> 2) & 1) ? 65 : 0, u = t & 3;
        bf16x8 z = {};
        *(bf16x8*)&xl[r][cc][u * 8] = z;
    }

    f32x4 acc[4];
    #pragma unroll
    for (int i = 0; i < 4; ++i) acc[i] = (f32x4){0.f, 0.f, 0.f, 0.f};

    int sw = t >> 2, su = t & 3;
    int spu = su ^ swz(sw + 1);

    for (int ch = c0; ch < c0 + NH; ++ch) {
        __syncthreads();
        #pragma unroll
        for (int r = 0; r < 3; ++r) {
            int hh = h + r - 1;
            bf16x8 v = {};
            if (hh >= 0 && hh < 64)
                v = *(const bf16x8*)(xprep + (((size_t)(b * NCH + ch)) * 64 + hh) * 64 * 32 + sw * 32 + su * 8);
            *(bf16x8*)&xl[r][sw + 1][spu * 8] = v;
        }
        __syncthreads();

        const short* wbase = wp + ((size_t)(ch * 9)) * 64 * 32;
        #pragma unroll
        for (int tap = 0; tap < 9; ++tap) {
            int kr = tap / 3, kc = tap % 3;
            bf16x8 a = *(const bf16x8*)(wbase + ((size_t)(tap * 64 + wv * 16 + n16)) * 32 + g * 8);
            #pragma unroll
            for (int nt = 0; nt < 4; ++nt) {
                int wpix = nt * 16 + n16 + kc;
                int pu = g ^ swz(wpix);
                bf16x8 bx = *(const bf16x8*)&xl[kr][wpix][pu * 8];
                acc[nt] = __builtin_amdgcn_mfma_f32_16x16x32_bf16(a, bx, acc[nt], 0, 0, 0);
            }
        }
    }

    float* y = ks ? y1 : y0;
    #pragma unroll
    for (int nt = 0; nt < 4; ++nt) {
        #pragma unroll
        for (int r = 0; r < 4; ++r) {
            int co = wv * 16 + g * 4 + r;
            y[((size_t)(b * CI + co)) * NPIX + h * 64 + nt * 16 + n16] = acc[nt][r];
        }
    }
}

template<int NCH>
__global__ __launch_bounds__(256) void k_convmfma(const short* __restrict__ xprep,
                                                  const short* __restrict__ wp,
                                                  float* __restrict__ y0,
                                                  float* __restrict__ y1) {
    conv_body<NCH>(xprep, wp, y0, y1, blockIdx.x, threadIdx.x);
}

// both conv2's in one dispatch
__global__ __launch_bounds__(256) void k_conv2x(const short* __restrict__ inA,
                                                const short* __restrict__ inB,
                                                const short* __restrict__ wp,
                                                float* a0, float* a1,
                                                float* b0, float* b1) {
    int blk = blockIdx.x;
    int w = blk >> 9;
    conv_body<2>(w ? inB : inA, wp, w ? b0 : a0, w ? b1 : a1, blk & 511, threadIdx.x);
}

// BN stats from two conv partials
__device__ __forceinline__ void bnstats_body(const float* __restrict__ y0,
                                             const float* __restrict__ y1,
                                             float* stats, int blk, int t) {
    int c = blk >> 2, b = blk & 3;
    size_t base = ((size_t)(b * 64 + c)) * NPIX;
    float s = 0.f, sq = 0.f;
    for (int i = t; i < NPIX; i += 256) {
        float v = y0[base + i] + y1[base + i];
        s += v; sq += v * v;
    }
    __shared__ float rs[8];
    for (int o = 32; o; o >>= 1) { s += __shfl_down(s, o); sq += __shfl_down(sq, o); }
    if ((t & 63) == 0) { rs[t >> 6] = s; rs[4 + (t >> 6)] = sq; }
    __syncthreads();
    if (t == 0) {
        atomicAdd(&stats[c], rs[0] + rs[1] + rs[2] + rs[3]);
        atomicAdd(&stats[64 + c], rs[4] + rs[5] + rs[6] + rs[7]);
    }
}

__global__ __launch_bounds__(256) void k_bnstats(const float* y0, const float* y1, float* stats) {
    bnstats_body(y0, y1, stats, blockIdx.x, threadIdx.x);
}
__global__ __launch_bounds__(256) void k_bnstats2x(const float* a0, const float* a1,
                                                   const float* b0, const float* b1,
                                                   float* sta, float* stb) {
    int blk = blockIdx.x;
    int w = blk >> 8;
    bnstats_body(w ? b0 : a0, w ? b1 : a1, w ? stb : sta, blk & 255, threadIdx.x);
}

__device__ __forceinline__ void bnapply_body(const float* y0, const float* y1,
                                             const float* stats, const float* g,
                                             const float* bta, float* out, int i) {
    int c = (i >> 12) & 63;
    float mean = stats[c] * (1.f / 16384.f);
    float var = stats[64 + c] * (1.f / 16384.f) - mean * mean;
    float rs = rsqrtf(var + 1e-5f);
    float v = (y0[i] + y1[i] - mean) * rs * g[c] + bta[c];
    out[i] = v > 0.f ? v : 0.f;
}

__global__ __launch_bounds__(256) void k_bnapply2(const float* y0, const float* y1,
                                                  const float* stats, const float* g,
                                                  const float* bta, float* out) {
    bnapply_body(y0, y1, stats, g, bta, out, blockIdx.x * 256 + threadIdx.x);
}
__global__ __launch_bounds__(256) void k_bnapply2x(const float* a0, const float* a1,
                                                   const float* b0, const float* b1,
                                                   const float* sta, const float* stb,
                                                   const float* g, const float* bta,
                                                   float* oa, float* ob) {
    int blk = blockIdx.x;
    int w = blk >> 12;
    int i = (blk & 4095) * 256 + threadIdx.x;
    bnapply_body(w ? b0 : a0, w ? b1 : a1, w ? stb : sta, g, bta, w ? ob : oa, i);
}

// q/k/v via MFMA body (256 virtual blocks)
__device__ __forceinline__ void qkv_body(const float* __restrict__ feat1,
                                         const short* __restrict__ wall,
                                         const float* __restrict__ ball,
                                         short* __restrict__ q,
                                         short* __restrict__ k,
                                         short* __restrict__ v, int blk, int t) {
    __shared__ __align__(16) short fl[64][64];
    int lane = t & 63, wv = t >> 6;
    int h = blk & 63, b = blk >> 6;
    int n16 = lane & 15, g = lane >> 4;

    {
        int n = t & 63, ug2 = t >> 6;
        const float* fp = feat1 + ((size_t)b * CI) * NPIX + h * 64 + n;
        #pragma unroll
        for (int uu = 0; uu < 2; ++uu) {
            int u = ug2 + uu * 4;
            int ci0 = u * 8;
            short tmp[8];
            #pragma unroll
            for (int j = 0; j < 8; ++j) tmp[j] = f2bs(fp[(size_t)(ci0 + j) * NPIX]);
            int phys = u ^ (n & 7);
            *(bf16x8*)&fl[n][phys * 8] = *(bf16x8*)tmp;
        }
    }
    __syncthreads();

    f32x4 acc[4];
    #pragma unroll
    for (int i = 0; i < 4; ++i) acc[i] = (f32x4){0.f, 0.f, 0.f, 0.f};
    f32x4 acc4 = (f32x4){0.f, 0.f, 0.f, 0.f};

    #pragma unroll
    for (int kc = 0; kc < 2; ++kc) {
        bf16x8 a = *(const bf16x8*)&wall[(size_t)(wv * 16 + n16) * 64 + kc * 32 + g * 8];
        bf16x8 a4 = *(const bf16x8*)&wall[(size_t)(64 + n16) * 64 + kc * 32 + g * 8];
        #pragma unroll
        for (int nt = 0; nt < 4; ++nt) {
            int n = nt * 16 + n16;
            int phys = (kc * 4 + g) ^ (n & 7);
            bf16x8 bx = *(const bf16x8*)&fl[n][phys * 8];
            acc[nt] = __builtin_amdgcn_mfma_f32_16x16x32_bf16(a, bx, acc[nt], 0, 0, 0);
            if (nt == wv) acc4 = __builtin_amdgcn_mfma_f32_16x16x32_bf16(a4, bx, acc4, 0, 0, 0);
        }
    }

    #pragma unroll
    for (int nt = 0; nt < 4; ++nt) {
        int pix = h * 64 + nt * 16 + n16;
        #pragma unroll
        for (int r = 0; r < 4; ++r) {
            int co = wv * 16 + g * 4 + r;
            short val = f2bs(acc[nt][r] + ball[co]);
            if (co < 8)       q[((size_t)(b * 8 + co)) * NPIX + pix] = val;
            else if (co < 16) k[((size_t)(b * 8 + co - 8)) * NPIX + pix] = val;
            else              v[((size_t)(b * 64 + co - 16)) * NPIX + pix] = val;
        }
    }
    {
        int pix = h * 64 + wv * 16 + n16;
        #pragma unroll
        for (int r = 0; r < 4; ++r) {
            int co = 64 + g * 4 + r;
            v[((size_t)(b * 64 + co - 16)) * NPIX + pix] = f2bs(acc4[r] + ball[co]);
        }
    }
}

// CAM gram partials body (256 virtual blocks)
__device__ __forceinline__ void gram_body(const float* __restrict__ f,
                                          float* __restrict__ gp, int blk, int t) {
    __shared__ __align__(16) float fl[64 * 68];
    int b = blk >> 6, nc = blk & 63;
    int n0 = nc * 64;
    int c = t & 63, dg = t >> 6;
    float acc[16];
    #pragma unroll
    for (int i = 0; i < 16; ++i) acc[i] = 0.f;
    for (int idx = t; idx < 4096; idx += 256) {
        int cc = idx >> 6, nn = idx & 63;
        fl[nn * 68 + cc] = f[((size_t)b * 64 + cc) * NPIX + n0 + nn];
    }
    __syncthreads();
    for (int nn = 0; nn < 64; ++nn) {
        float fc = fl[nn * 68 + c];
        const float4* fd = (const float4*)(fl + nn * 68 + dg * 16);
        #pragma unroll
        for (int k4 = 0; k4 < 4; ++k4) {
            float4 vv = fd[k4];
            acc[k4 * 4 + 0] += fc * vv.x;
            acc[k4 * 4 + 1] += fc * vv.y;
            acc[k4 * 4 + 2] += fc * vv.z;
            acc[k4 * 4 + 3] += fc * vv.w;
        }
    }
    float* dst = gp + (size_t)nc * 16384 + ((size_t)b * 64 + c) * 64 + dg * 16;
    #pragma unroll
    for (int kk = 0; kk < 16; ++kk) dst[kk] = acc[kk];
}

// fused qkv + gram (both read feat1 only)
__global__ __launch_bounds__(256) void k_qkvgram(const float* __restrict__ feat1,
                                                 const short* __restrict__ wall,
                                                 const float* __restrict__ ball,
                                                 short* q, short* k, short* v,
                                                 float* gp) {
    int blk = blockIdx.x, t = threadIdx.x;
    if (blk < 256) qkv_body(feat1, wall, ball, q, k, v, blk, t);
    else gram_body(feat1, gp, blk - 256, t);
}

// PAM partial pass: 128-wide j rounds, swapped QK, direct-global V.
// kl rows padded to 40B (write 16-way -> 4-way; reads as 2x bf16x4, conflict-free);
// pl [64][128] with 16B-unit XOR swizzle keyed on row&7 (PV reads 8-way -> ~2-way).
__global__ __launch_bounds__(256) void k_pampart(const short* __restrict__ q,
                                                 const short* __restrict__ k,
                                                 const short* __restrict__ v,
                                                 short* __restrict__ po,
                                                 float* __restrict__ pl_acc) {
    __shared__ short kl[128][20];                // [j][d0..15 + pad]; 40B rows
    __shared__ __align__(16) short pl[64][128];  // [i][j], unit-swizzled

    int t = threadIdx.x;
    int lane = t & 63, w = t >> 6;
    int blk = blockIdx.x;
    int jc = blk >> 8, b = (blk >> 6) & 3, ic = blk & 63;
    int i0 = ic * 64;
    int n16 = lane & 15, g = lane >> 4;
    int key = n16 & 7;

    const short* qb = q + (size_t)b * 8 * NPIX;
    const short* kb = k + (size_t)b * 8 * NPIX;
    const short* vb = v + (size_t)b * 64 * NPIX;

    // zero kl d8..15 (u32 slots 4..7) once
    #pragma unroll
    for (int i = 0; i < 2; ++i) {
        int idx = i * 256 + t;
        int jj = idx & 127, dz = 8 + ((idx >> 7) << 1);
        *(unsigned*)&kl[jj][dz] = 0u;
    }

    // aq as B-operand: lane<16 holds q[d=e][i0+w*16+lane]
    bf16x8 aq = {};
    if (lane < 16) {
        int irow = i0 + w * 16 + lane;
        #pragma unroll
        for (int e = 0; e < 8; ++e) aq[e] = qb[(size_t)e * NPIX + irow];
    }

    f32x4 acc[4];
    #pragma unroll
    for (int i = 0; i < 4; ++i) acc[i] = (f32x4){0.f, 0.f, 0.f, 0.f};
    float lacc = 0.f;
    const f32x4 zz = {0.f, 0.f, 0.f, 0.f};

    for (int ro = 0; ro < 8; ++ro) {
        int j0 = jc * 1024 + ro * 128;
        // stage K (128j x 8d) as u32 (d-pairs); 40B rows -> 4-way writes
        #pragma unroll
        for (int i = 0; i < 2; ++i) {
            int idx = i * 256 + t;
            int jj = idx & 127, dp2 = idx >> 7;
            unsigned lo = (unsigned short)kb[(size_t)(dp2 * 2) * NPIX + j0 + jj];
            unsigned hi = (unsigned short)kb[(size_t)(dp2 * 2 + 1) * NPIX + j0 + jj];
            *(unsigned*)&kl[jj][dp2 * 2] = lo | (hi << 16);
        }
        // V fragments direct from global (issue early; consumed after next barrier)
        bf16x8 av[4];
        #pragma unroll
        for (int ks = 0; ks < 4; ++ks)
            av[ks] = *(const bf16x8*)&vb[(size_t)(w * 16 + n16) * NPIX + j0 + ks * 32 + g * 8];
        __syncthreads();

        // swapped QK: mfma(K,Q) -> D[j][i]; lane holds 4 consecutive j at col i=n16
        __builtin_amdgcn_s_setprio(1);
        #pragma unroll
        for (int jsub = 0; jsub < 8; ++jsub) {
            bf16x8 bk = {};
            if (lane < 32) {
                bf16x4 lo = *(const bf16x4*)&kl[jsub * 16 + n16][g * 8];
                bf16x4 hi = *(const bf16x4*)&kl[jsub * 16 + n16][g * 8 + 4];
                bk = __builtin_shufflevector(lo, hi, 0, 1, 2, 3, 4, 5, 6, 7);
            }
            f32x4 s = __builtin_amdgcn_mfma_f32_16x16x32_bf16(bk, aq, zz, 0, 0, 0);
            float e0 = exp2f(s[0]), e1 = exp2f(s[1]), e2 = exp2f(s[2]), e3 = exp2f(s[3]);
            lacc += (e0 + e1) + (e2 + e3);
            bf16x4 pk = { f2bs(e0), f2bs(e1), f2bs(e2), f2bs(e3) };
            int uw = (jsub * 2 + (g >> 1)) ^ key;        // 16B-unit XOR swizzle
            *(bf16x4*)&pl[w * 16 + n16][uw * 8 + (g & 1) * 4] = pk;
        }
        __builtin_amdgcn_s_setprio(0);
        __syncthreads();

        // O^T += V * P^T (16 MFMA), swizzled pl reads
        __builtin_amdgcn_s_setprio(1);
        #pragma unroll
        for (int isub = 0; isub < 4; ++isub) {
            #pragma unroll
            for (int ks = 0; ks < 4; ++ks) {
                int ur = (ks * 4 + g) ^ key;
                bf16x8 bp = *(const bf16x8*)&pl[isub * 16 + n16][ur * 8];
                acc[isub] = __builtin_amdgcn_mfma_f32_16x16x32_bf16(av[ks], bp, acc[isub], 0, 0, 0);
            }
        }
        __builtin_amdgcn_s_setprio(0);
        __syncthreads();
    }

    // l reduce: lanes {n16, n16+16, n16+32, n16+48} share row i0+w*16+n16
    {
        float lv = lacc;
        lv += __shfl_xor(lv, 16);
        lv += __shfl_xor(lv, 32);
        if (lane < 16)
            atomicAdd(&pl_acc[b * NPIX + i0 + w * 16 + lane], lv);
    }

    #pragma unroll
    for (int isub = 0; isub < 4; ++isub) {
        #pragma unroll
        for (int r = 0; r < 4; ++r) {
            int c = w * 16 + g * 4 + r;
            size_t o = ((size_t)((jc * BB + b) * 64 + c)) * NPIX + i0 + isub * 16 + n16;
            po[o] = f2bs(acc[isub][r]);
        }
    }
}

// fused gram-reduce + channel softmax
__global__ void k_camsm2(const float* __restrict__ gp, float* __restrict__ cattn) {
    int row = blockIdx.x;
    int d = threadIdx.x;
    float v = 0.f;
    #pragma unroll 8
    for (int p = 0; p < 64; ++p) v += gp[(size_t)p * 16384 + row * 64 + d];
    float mn = v;
    for (int s = 32; s; s >>= 1) mn = fminf(mn, __shfl_xor(mn, s));
    float e = exp2f((mn - v) * LOG2E);
    float sum = e;
    for (int s = 32; s; s >>= 1) sum += __shfl_xor(sum, s);
    cattn[(size_t)row * 64 + d] = e / sum;
}

// sc_feat = gamma_cam * (cattn @ f) + feat1
__global__ __launch_bounds__(256) void k_cam(const float* __restrict__ cattn,
                                             const float* __restrict__ f,
                                             const float* __restrict__ gcp,
                                             float* __restrict__ sc) {
    __shared__ __align__(16) float Al[64 * 68];
    __shared__ float fl[64 * 64];
    int blk = blockIdx.x;
    int b = blk >> 6, nc = blk & 63;
    int n0 = nc * 64;
    int t = threadIdx.x;
    int nl = t & 63, cg = t >> 6;
    for (int idx = t; idx < 4096; idx += 256) {
        int cc = idx >> 6, dd = idx & 63;
        Al[dd * 68 + cc] = cattn[((size_t)b * 64 + cc) * 64 + dd];
    }
    for (int idx = t; idx < 4096; idx += 256) {
        int dd = idx >> 6, nn = idx & 63;
        fl[dd * 64 + nn] = f[((size_t)b * 64 + dd) * NPIX + n0 + nn];
    }
    __syncthreads();
    float acc[16];
    #pragma unroll
    for (int i = 0; i < 16; ++i) acc[i] = 0.f;
    for (int d = 0; d < 64; ++d) {
        float fv = fl[d * 64 + nl];
        const float4* A4 = (const float4*)(Al + d * 68 + cg * 16);
        #pragma unroll
        for (int k4 = 0; k4 < 4; ++k4) {
            float4 a = A4[k4];
            acc[k4 * 4 + 0] += a.x * fv;
            acc[k4 * 4 + 1] += a.y * fv;
            acc[k4 * 4 + 2] += a.z * fv;
            acc[k4 * 4 + 3] += a.w * fv;
        }
    }
    float g = gcp[0];
    #pragma unroll
    for (int kk = 0; kk < 16; ++kk) {
        int c = cg * 16 + kk;
        size_t o = ((size_t)b * 64 + c) * NPIX + n0 + nl;
        sc[o] = g * acc[kk] + f[o];
    }
}

// out = w8 @ (sa_conv + sc_conv) + b8 via MFMA (1x1, 64 -> 256)
__global__ __launch_bounds__(256) void k_finalmfma(const float* __restrict__ sa,
                                                   const float* __restrict__ sc,
                                                   const short* __restrict__ w8p,
                                                   const float* __restrict__ b8,
                                                   float* __restrict__ out) {
    __shared__ __align__(16) short fl[64][64];
    int t = threadIdx.x;
    int lane = t & 63, wv = t >> 6;
    int blk = blockIdx.x;
    int h = blk & 63, b = (blk >> 6) & 3, cq = blk >> 8;
    int n16 = lane & 15, g = lane >> 4;

    {
        int n = t & 63, ug2 = t >> 6;
        const float* sap = sa + ((size_t)b * CI) * NPIX + h * 64 + n;
        const float* scp = sc + ((size_t)b * CI) * NPIX + h * 64 + n;
        #pragma unroll
        for (int uu = 0; uu < 2; ++uu) {
            int u = ug2 + uu * 4;
            int ci0 = u * 8;
            short tmp[8];
            #pragma unroll
            for (int j = 0; j < 8; ++j) {
                size_t o = (size_t)(ci0 + j) * NPIX;
                tmp[j] = f2bs(sap[o] + scp[o]);
            }
            int phys = u ^ (n & 7);
            *(bf16x8*)&fl[n][phys * 8] = *(bf16x8*)tmp;
        }
    }
    __syncthreads();

    f32x4 acc[4];
    #pragma unroll
    for (int i = 0; i < 4; ++i) acc[i] = (f32x4){0.f, 0.f, 0.f, 0.f};
    int cobase = cq * 64 + wv * 16;

    #pragma unroll
    for (int kc = 0; kc < 2; ++kc) {
        bf16x8 a = *(const bf16x8*)&w8p[(size_t)(cobase + n16) * 64 + kc * 32 + g * 8];
        #pragma unroll
        for (int nt = 0; nt < 4; ++nt) {
            int n = nt * 16 + n16;
            int phys = (kc * 4 + g) ^ (n & 7);
            bf16x8 bx = *(const bf16x8*)&fl[n][phys * 8];
            acc[nt] = __builtin_amdgcn_mfma_f32_16x16x32_bf16(a, bx, acc[nt], 0, 0, 0);
        }
    }

    #pragma unroll
    for (int nt = 0; nt < 4; ++nt) {
        #pragma unroll
        for (int r = 0; r < 4; ++r) {
            int co = cobase + g * 4 + r;
            out[((size_t)(b * COUT + co)) * NPIX + h * 64 + nt * 16 + n16] = acc[nt][r] + b8[co];
        }
    }
}

// ---------------- launcher ----------------
extern "C" void kernel_launch(void* const* d_in, const int* in_sizes, int n_in,
                              void* d_out, int out_size, void* d_ws, size_t ws_size,
                              hipStream_t stream) {
    (void)in_sizes; (void)n_in; (void)out_size; (void)ws_size;
    const float* x    = (const float*)d_in[0];
    const float* w1   = (const float*)d_in[1];
    const float* bng  = (const float*)d_in[2];
    const float* bnb  = (const float*)d_in[3];
    const float* wq   = (const float*)d_in[4];
    const float* bq   = (const float*)d_in[5];
    const float* wk   = (const float*)d_in[6];
    const float* bk   = (const float*)d_in[7];
    const float* wv   = (const float*)d_in[8];
    const float* bv   = (const float*)d_in[9];
    const float* gpam = (const float*)d_in[10];
    const float* gcam = (const float*)d_in[11];
    const float* w2   = (const float*)d_in[12];
    const float* w8   = (const float*)d_in[13];
    const float* b8   = (const float*)d_in[14];
    float* out = (float*)d_out;

    char* WB = (char*)d_ws;
    float* fC1P0   = (float*)(WB + B_Y1V);            // conv1 p0
    float* fC1P1   = (float*)(WB + B_SACONV);         // conv1 p1
    float* fGP     = (float*)(WB + B_SACONV);         // gram partials (4MB, after C1P1 dies)
    short* fV      = (short*)(WB + B_Y1V);            // V bf16 (2MB)
    short* fSPREPSC= (short*)(WB + B_Y1V + 0x200000); // sc-prep bf16 (2MB)
    short* fSAPREP = (short*)(WB + B_Y1V);            // sa-prep bf16 (2MB, after V dies)
    float* fFEAT1  = (float*)(WB + B_FEAT1);
    short* fXPREP  = (short*)(WB + B_SA);             // 8MB spanning SA+Y2
    float* fSCFEAT = (float*)(WB + B_SA);
    float* fC2B1   = (float*)(WB + B_SA);             // conv2b p1; SCCONV in-place
    short* fPO     = (short*)(WB + B_Y2);             // 8MB spanning Y2+SACONV
    float* fC2A0   = (float*)(WB + B_Y2);             // conv2a p0
    float* fC2B0   = (float*)(WB + B_FEAT1);          // conv2b p0 (feat1 dead)
    float* fC2A1   = (float*)(WB + B_SACONV);         // conv2a p1; SACONV in-place
    short* fQ      = (short*)(WB + B_Q);
    short* fK      = (short*)(WB + B_K);
    float* fST     = (float*)(WB + B_ST);
    float* fST2a   = fST + 128;
    float* fST2b   = fST + 256;
    float* fCATT   = (float*)(WB + B_CATT);
    short* fWP1    = (short*)(WB + B_WP1);
    short* fWP2    = (short*)(WB + B_WP2);
    float* fPL     = (float*)(WB + B_PL);
    short* fW8P    = (short*)(WB + B_W8P);
    short* fWQKV   = (short*)(WB + B_WQKV);
    float* fBALL   = (float*)(WB + B_BALL);

    k_prepw<<<1382, 256, 0, stream>>>(x, w1, w2, w8, wq, bq, wk, bk, wv, bv,
                                      fXPREP, fWP1, fWP2, fW8P, fWQKV, fBALL, fST, fPL);

    k_convmfma<8><<<512, 256, 0, stream>>>(fXPREP, fWP1, fC1P0, fC1P1);
    k_bnstats<<<256, 256, 0, stream>>>(fC1P0, fC1P1, fST);
    k_bnapply2<<<4096, 256, 0, stream>>>(fC1P0, fC1P1, fST, bng, bnb, fFEAT1);

    k_qkvgram<<<512, 256, 0, stream>>>(fFEAT1, fWQKV, fBALL, fQ, fK, fV, fGP);
    k_camsm2<<<256, 64, 0, stream>>>(fGP, fCATT);        // GP consumed before PO clobbers it

    k_pampart<<<1024, 256, 0, stream>>>(fQ, fK, fV, fPO, fPL);
    k_cam<<<256, 256, 0, stream>>>(fCATT, fFEAT1, gcam, fSCFEAT);
    k_preppam<<<256, 256, 0, stream>>>(fSCFEAT, fSPREPSC, fPO, fPL, fFEAT1, gpam, fSAPREP);

    k_conv2x<<<1024, 256, 0, stream>>>(fSAPREP, fSPREPSC, fWP2, fC2A0, fC2A1, fC2B0, fC2B1);
    k_bnstats2x<<<512, 256, 0, stream>>>(fC2A0, fC2A1, fC2B0, fC2B1, fST2a, fST2b);
    k_bnapply2x<<<8192, 256, 0, stream>>>(fC2A0, fC2A1, fC2B0, fC2B1, fST2a, fST2b,
                                          bng, bnb, fC2A1, fC2B1);

    k_finalmfma<<<1024, 256, 0, stream>>>(fC2A1, fC2B1, fW8P, b8, out);
}

// Round 16
// 135.078 us; speedup vs baseline: 1.1070x; 1.0095x over previous
//
#include <hip/hip_runtime.h>
#include <hip/hip_bf16.h>

// ---------------- problem constants ----------------
#define BB   4
#define CIN  256
#define CI   64
#define COUT 256
#define NPIX 4096          // 64*64
#define LOG2E 1.44269504088896340736f

// ---------------- ws layout (BYTE offsets) ----------------
#define B_Y1V    0x0000000u  // 4MB: conv1-p0 f32 -> {V bf16 @0, SPREP_SC bf16 @2MB} -> SAPREP bf16 @0
#define B_FEAT1  0x0400000u  // 4MB f32 feat1; later conv2b-p0
#define B_SA     0x0800000u  // 4MB: xprep head; conv2b-p1 (in-place SCCONV)
#define B_Y2     0x0C00000u  // 4MB: xprep tail; PO head; conv2a-p0
#define B_SACONV 0x1000000u  // 4MB: conv1-p1; GP f32; PO tail; conv2a-p1 (in-place SACONV)
#define B_Q      0x1400000u  // 256KB bf16[131072] (q, LOG2E-prescaled)
#define B_K      0x1480000u  // 256KB bf16
#define B_ST     0x15A0000u  // 1.5KB f32[384]
#define B_CATT   0x15B1000u  // 64KB
#define B_WP1    0x15C1000u  // 288KB bf16[147456]
#define B_WP2    0x1610000u  // 72KB  bf16[36864]
#define B_PL     0x1630000u  // 64KB f32[16384] partial-l accumulator
#define B_W8P    0x1640000u  // 32KB bf16[16384]
#define B_WQKV   0x1648000u  // 10KB bf16[5120]
#define B_BALL   0x164B000u  // 320B f32[80]

typedef __attribute__((ext_vector_type(8))) short bf16x8;
typedef __attribute__((ext_vector_type(4))) short bf16x4;
typedef __attribute__((ext_vector_type(4))) float f32x4;

__device__ __forceinline__ short f2bs(float f) {
    union { float f; unsigned u; } c; c.f = f;
    unsigned r = c.u + 0x7FFFu + ((c.u >> 16) & 1u);
    return (short)(r >> 16);
}
__device__ __forceinline__ float bs2f(unsigned short s) {
    union { unsigned u; float f; } c; c.u = ((unsigned)s) << 16;
    return c.f;
}
__device__ __forceinline__ int swz(int wp) { return (wp ^ (wp >> 2)) & 3; }

// ---------------- bodies ----------------

// weight-prep + zeroing (870 virtual blocks)
__device__ __forceinline__ void weights_body(const float* __restrict__ w1,
                                             const float* __restrict__ w2,
                                             const float* __restrict__ w8,
                                             const float* wq, const float* bq,
                                             const float* wk, const float* bk,
                                             const float* wv, const float* bv,
                                             short* wp1, short* wp2, short* w8p,
                                             short* wall, float* ball,
                                             float* st, float* pl, int blk, int t) {
    if (blk < 576) {
        int idx = blk * 256 + t;
        if (idx < 147456) {
            int cil = idx & 31, co = (idx >> 5) & 63;
            int rest = idx >> 11, tap = rest % 9, ch = rest / 9;
            wp1[idx] = f2bs(w1[co * CIN * 9 + (ch * 32 + cil) * 9 + tap]);
        }
    } else if (blk < 720) {
        int idx = (blk - 576) * 256 + t;
        if (idx < 36864) {
            int cil = idx & 31, co = (idx >> 5) & 63;
            int rest = idx >> 11, tap = rest % 9, ch = rest / 9;
            wp2[idx] = f2bs(w2[co * CI * 9 + (ch * 32 + cil) * 9 + tap]);
        }
    } else if (blk < 784) {
        int idx = (blk - 720) * 256 + t;
        w8p[idx] = f2bs(w8[idx]);
    } else if (blk < 804) {
        int idx = (blk - 784) * 256 + t;
        if (idx < 5120) {
            int co = idx >> 6, ci = idx & 63;
            float v;
            if (co < 8)       v = wq[co * 64 + ci] * LOG2E;
            else if (co < 16) v = wk[(co - 8) * 64 + ci];
            else              v = wv[(co - 16) * 64 + ci];
            wall[idx] = f2bs(v);
        }
        if (idx < 80) {
            float v;
            if (idx < 8)       v = bq[idx] * LOG2E;
            else if (idx < 16) v = bk[idx - 8];
            else               v = bv[idx - 16];
            ball[idx] = v;
        }
    } else if (blk < 806) {
        int idx = (blk - 804) * 256 + t;
        if (idx < 384) st[idx] = 0.f;
    } else {
        int idx = (blk - 806) * 256 + t;
        pl[idx] = 0.f;
    }
}

// transpose f32 [b][NCH*32 ci][4096] -> bf16 [b][NCH][h][w][ci32]
template<int NCH>
__device__ __forceinline__ void prep_body(const float* __restrict__ in,
                                          short* __restrict__ out, int blk, int t) {
    __shared__ short tl[4][64][34];
    int hq = blk & 15;
    int ch = (blk >> 4) % NCH;
    int b  = blk / (16 * NCH);
    const int CINT = NCH * 32;

    #pragma unroll
    for (int i = 0; i < 32; ++i) {
        int idx = i * 256 + t;
        int w = idx & 63, hh = (idx >> 6) & 3, ci = idx >> 8;
        float v = in[((size_t)(b * CINT + ch * 32 + ci)) * NPIX + (hq * 4 + hh) * 64 + w];
        tl[hh][w][ci] = f2bs(v);
    }
    __syncthreads();
    unsigned* outu = (unsigned*)(out + (((size_t)(b * NCH + ch)) * NPIX + hq * 4 * 64) * 32);
    #pragma unroll
    for (int i = 0; i < 16; ++i) {
        int j = i * 256 + t;
        int cip = j & 15, w = (j >> 4) & 63, hh = j >> 10;
        unsigned v = *(unsigned*)&tl[hh][w][2 * cip];
        outu[(size_t)(hh * 64 + w) * 16 + cip] = v;
    }
}

// fused weights + prep<8>
__global__ __launch_bounds__(256) void k_prepw(const float* __restrict__ x,
                                               const float* w1, const float* w2, const float* w8,
                                               const float* wq, const float* bq,
                                               const float* wk, const float* bk,
                                               const float* wv, const float* bv,
                                               short* xprep,
                                               short* wp1, short* wp2, short* w8p,
                                               short* wall, float* ball,
                                               float* st, float* pl) {
    int blk = blockIdx.x, t = threadIdx.x;
    if (blk < 512) prep_body<8>(x, xprep, blk, t);
    else weights_body(w1, w2, w8, wq, bq, wk, bk, wv, bv,
                      wp1, wp2, w8p, wall, ball, st, pl, blk - 512, t);
}

// PAM-merge + prep: sa = feat1 + g*(sum_jc PO)/PL -> bf16 [b][2][h][w][ci32]
__device__ __forceinline__ void pamprep_body(const short* __restrict__ po,
                                             const float* __restrict__ pl_acc,
                                             const float* __restrict__ feat1,
                                             const float* __restrict__ gp,
                                             short* __restrict__ out, int blk, int t) {
    __shared__ short tl[4][64][34];
    int hq = blk & 15;
    int ch = (blk >> 4) & 1;
    int b  = blk >> 5;
    float g = gp[0];

    #pragma unroll
    for (int i = 0; i < 32; ++i) {
        int idx = i * 256 + t;
        int w = idx & 63, hh = (idx >> 6) & 3, ci = idx >> 8;
        int pix = (hq * 4 + hh) * 64 + w;
        size_t o = ((size_t)(b * 64 + ch * 32 + ci)) * NPIX + pix;
        float s = bs2f((unsigned short)po[o])
                + bs2f((unsigned short)po[o + 1048576])
                + bs2f((unsigned short)po[o + 2097152])
                + bs2f((unsigned short)po[o + 3145728]);
        float v = feat1[o] + g * s / pl_acc[b * NPIX + pix];
        tl[hh][w][ci] = f2bs(v);
    }
    __syncthreads();
    unsigned* outu = (unsigned*)(out + (((size_t)(b * 2 + ch)) * NPIX + hq * 4 * 64) * 32);
    #pragma unroll
    for (int i = 0; i < 16; ++i) {
        int j = i * 256 + t;
        int cip = j & 15, w = (j >> 4) & 63, hh = j >> 10;
        unsigned v = *(unsigned*)&tl[hh][w][2 * cip];
        outu[(size_t)(hh * 64 + w) * 16 + cip] = v;
    }
}

// CAM apply fused with prep: sc = g*(cattn@f) + f, written directly as
// bf16 prep layout [b][2][pix][ci32]. 256 virtual blocks (b, 64-pixel tile).
__device__ __forceinline__ void camprep_body(const float* __restrict__ cattn,
                                             const float* __restrict__ f,
                                             const float* __restrict__ gcp,
                                             short* __restrict__ out, int blk, int t) {
    __shared__ __align__(16) float Al[64 * 68];
    __shared__ float fl[64 * 64];
    int b = blk >> 6, nc = blk & 63;
    int n0 = nc * 64;
    int nl = t & 63, cg = t >> 6;
    for (int idx = t; idx < 4096; idx += 256) {
        int cc = idx >> 6, dd = idx & 63;
        Al[dd * 68 + cc] = cattn[((size_t)b * 64 + cc) * 64 + dd];
    }
    for (int idx = t; idx < 4096; idx += 256) {
        int dd = idx >> 6, nn = idx & 63;
        fl[dd * 64 + nn] = f[((size_t)b * 64 + dd) * NPIX + n0 + nn];
    }
    __syncthreads();
    float acc[16];
    #pragma unroll
    for (int i = 0; i < 16; ++i) acc[i] = 0.f;
    for (int d = 0; d < 64; ++d) {
        float fv = fl[d * 64 + nl];
        const float4* A4 = (const float4*)(Al + d * 68 + cg * 16);
        #pragma unroll
        for (int k4 = 0; k4 < 4; ++k4) {
            float4 a = A4[k4];
            acc[k4 * 4 + 0] += a.x * fv;
            acc[k4 * 4 + 1] += a.y * fv;
            acc[k4 * 4 + 2] += a.z * fv;
            acc[k4 * 4 + 3] += a.w * fv;
        }
    }
    float g = gcp[0];
    int pix = n0 + nl;
    unsigned* du = (unsigned*)out + ((size_t)(b * 2 + (cg >> 1)) * NPIX + pix) * 16 + (cg & 1) * 8;
    #pragma unroll
    for (int m = 0; m < 8; ++m) {
        float v0 = g * acc[2 * m]     + fl[(cg * 16 + 2 * m) * 64 + nl];
        float v1 = g * acc[2 * m + 1] + fl[(cg * 16 + 2 * m + 1) * 64 + nl];
        du[m] = (unsigned)(unsigned short)f2bs(v0) | ((unsigned)(unsigned short)f2bs(v1) << 16);
    }
}

// fused camprep + pamprep (both ready after camsm2 + pampart)
__global__ __launch_bounds__(256) void k_campam(const float* __restrict__ cattn,
                                                const float* __restrict__ feat1,
                                                const float* __restrict__ gcp,
                                                short* __restrict__ sprep_sc,
                                                const short* __restrict__ po,
                                                const float* __restrict__ pl_acc,
                                                const float* __restrict__ gpam,
                                                short* __restrict__ saprep) {
    int blk = blockIdx.x, t = threadIdx.x;
    if (blk < 256) camprep_body(cattn, feat1, gcp, sprep_sc, blk, t);
    else pamprep_body(po, pl_acc, feat1, gpam, saprep, blk - 256, t);
}

// 3x3 SAME conv via MFMA, K-split body: blk in [0,512): ks=blk>>8, b, h
template<int NCH>
__device__ __forceinline__ void conv_body(const short* __restrict__ xprep,
                                          const short* __restrict__ wp,
                                          float* __restrict__ y0,
                                          float* __restrict__ y1,
                                          int blk, int t) {
    __shared__ __align__(16) short xl[3][66][32];
    int lane = t & 63, wv = t >> 6;
    int ks = blk >> 8;
    int b = (blk >> 6) & 3, h = blk & 63;
    int g = lane >> 4, n16 = lane & 15;
    constexpr int NH = NCH / 2;
    int c0 = ks * NH;

    if (t < 24) {
        int r = t >> 3, cc = ((t >> 2) & 1) ? 65 : 0, u = t & 3;
        bf16x8 z = {};
        *(bf16x8*)&xl[r][cc][u * 8] = z;
    }

    f32x4 acc[4];
    #pragma unroll
    for (int i = 0; i < 4; ++i) acc[i] = (f32x4){0.f, 0.f, 0.f, 0.f};

    int sw = t >> 2, su = t & 3;
    int spu = su ^ swz(sw + 1);

    for (int ch = c0; ch < c0 + NH; ++ch) {
        __syncthreads();
        #pragma unroll
        for (int r = 0; r < 3; ++r) {
            int hh = h + r - 1;
            bf16x8 v = {};
            if (hh >= 0 && hh < 64)
                v = *(const bf16x8*)(xprep + (((size_t)(b * NCH + ch)) * 64 + hh) * 64 * 32 + sw * 32 + su * 8);
            *(bf16x8*)&xl[r][sw + 1][spu * 8] = v;
        }
        __syncthreads();

        const short* wbase = wp + ((size_t)(ch * 9)) * 64 * 32;
        #pragma unroll
        for (int tap = 0; tap < 9; ++tap) {
            int kr = tap / 3, kc = tap % 3;
            bf16x8 a = *(const bf16x8*)(wbase + ((size_t)(tap * 64 + wv * 16 + n16)) * 32 + g * 8);
            #pragma unroll
            for (int nt = 0; nt < 4; ++nt) {
                int wpix = nt * 16 + n16 + kc;
                int pu = g ^ swz(wpix);
                bf16x8 bx = *(const bf16x8*)&xl[kr][wpix][pu * 8];
                acc[nt] = __builtin_amdgcn_mfma_f32_16x16x32_bf16(a, bx, acc[nt], 0, 0, 0);
            }
        }
    }

    float* y = ks ? y1 : y0;
    #pragma unroll
    for (int nt = 0; nt < 4; ++nt) {
        #pragma unroll
        for (int r = 0; r < 4; ++r) {
            int co = wv * 16 + g * 4 + r;
            y[((size_t)(b * CI + co)) * NPIX + h * 64 + nt * 16 + n16] = acc[nt][r];
        }
    }
}

template<int NCH>
__global__ __launch_bounds__(256) void k_convmfma(const short* __restrict__ xprep,
                                                  const short* __restrict__ wp,
                                                  float* __restrict__ y0,
                                                  float* __restrict__ y1) {
    conv_body<NCH>(xprep, wp, y0, y1, blockIdx.x, threadIdx.x);
}

// both conv2's in one dispatch
__global__ __launch_bounds__(256) void k_conv2x(const short* __restrict__ inA,
                                                const short* __restrict__ inB,
                                                const short* __restrict__ wp,
                                                float* a0, float* a1,
                                                float* b0, float* b1) {
    int blk = blockIdx.x;
    int w = blk >> 9;
    conv_body<2>(w ? inB : inA, wp, w ? b0 : a0, w ? b1 : a1, blk & 511, threadIdx.x);
}

// BN stats from two conv partials: 1024 virtual blocks = 64c x 4b x 4 pixel-chunks
__device__ __forceinline__ void bnstats_body(const float* __restrict__ y0,
                                             const float* __restrict__ y1,
                                             float* stats, int blk, int t) {
    int pc = blk & 3;
    int cb = blk >> 2;
    int c = cb >> 2, b = cb & 3;
    size_t base = ((size_t)(b * 64 + c)) * NPIX + pc * 1024;
    float s = 0.f, sq = 0.f;
    #pragma unroll
    for (int i = 0; i < 4; ++i) {
        float v = y0[base + i * 256 + t] + y1[base + i * 256 + t];
        s += v; sq += v * v;
    }
    __shared__ float rs[8];
    for (int o = 32; o; o >>= 1) { s += __shfl_down(s, o); sq += __shfl_down(sq, o); }
    if ((t & 63) == 0) { rs[t >> 6] = s; rs[4 + (t >> 6)] = sq; }
    __syncthreads();
    if (t == 0) {
        atomicAdd(&stats[c], rs[0] + rs[1] + rs[2] + rs[3]);
        atomicAdd(&stats[64 + c], rs[4] + rs[5] + rs[6] + rs[7]);
    }
}

__global__ __launch_bounds__(256) void k_bnstats(const float* y0, const float* y1, float* stats) {
    bnstats_body(y0, y1, stats, blockIdx.x, threadIdx.x);
}
__global__ __launch_bounds__(256) void k_bnstats2x(const float* a0, const float* a1,
                                                   const float* b0, const float* b1,
                                                   float* sta, float* stb) {
    int blk = blockIdx.x;
    int w = blk >> 10;
    bnstats_body(w ? b0 : a0, w ? b1 : a1, w ? stb : sta, blk & 1023, threadIdx.x);
}

__device__ __forceinline__ void bnapply_body(const float* y0, const float* y1,
                                             const float* stats, const float* g,
                                             const float* bta, float* out, int i) {
    int c = (i >> 12) & 63;
    float mean = stats[c] * (1.f / 16384.f);
    float var = stats[64 + c] * (1.f / 16384.f) - mean * mean;
    float rs = rsqrtf(var + 1e-5f);
    float v = (y0[i] + y1[i] - mean) * rs * g[c] + bta[c];
    out[i] = v > 0.f ? v : 0.f;
}

__global__ __launch_bounds__(256) void k_bnapply2(const float* y0, const float* y1,
                                                  const float* stats, const float* g,
                                                  const float* bta, float* out) {
    bnapply_body(y0, y1, stats, g, bta, out, blockIdx.x * 256 + threadIdx.x);
}
__global__ __launch_bounds__(256) void k_bnapply2x(const float* a0, const float* a1,
                                                   const float* b0, const float* b1,
                                                   const float* sta, const float* stb,
                                                   const float* g, const float* bta,
                                                   float* oa, float* ob) {
    int blk = blockIdx.x;
    int w = blk >> 12;
    int i = (blk & 4095) * 256 + threadIdx.x;
    bnapply_body(w ? b0 : a0, w ? b1 : a1, w ? stb : sta, g, bta, w ? ob : oa, i);
}

// q/k/v via MFMA body (256 virtual blocks)
__device__ __forceinline__ void qkv_body(const float* __restrict__ feat1,
                                         const short* __restrict__ wall,
                                         const float* __restrict__ ball,
                                         short* __restrict__ q,
                                         short* __restrict__ k,
                                         short* __restrict__ v, int blk, int t) {
    __shared__ __align__(16) short fl[64][64];
    int lane = t & 63, wv = t >> 6;
    int h = blk & 63, b = blk >> 6;
    int n16 = lane & 15, g = lane >> 4;

    {
        int n = t & 63, ug2 = t >> 6;
        const float* fp = feat1 + ((size_t)b * CI) * NPIX + h * 64 + n;
        #pragma unroll
        for (int uu = 0; uu < 2; ++uu) {
            int u = ug2 + uu * 4;
            int ci0 = u * 8;
            short tmp[8];
            #pragma unroll
            for (int j = 0; j < 8; ++j) tmp[j] = f2bs(fp[(size_t)(ci0 + j) * NPIX]);
            int phys = u ^ (n & 7);
            *(bf16x8*)&fl[n][phys * 8] = *(bf16x8*)tmp;
        }
    }
    __syncthreads();

    f32x4 acc[4];
    #pragma unroll
    for (int i = 0; i < 4; ++i) acc[i] = (f32x4){0.f, 0.f, 0.f, 0.f};
    f32x4 acc4 = (f32x4){0.f, 0.f, 0.f, 0.f};

    #pragma unroll
    for (int kc = 0; kc < 2; ++kc) {
        bf16x8 a = *(const bf16x8*)&wall[(size_t)(wv * 16 + n16) * 64 + kc * 32 + g * 8];
        bf16x8 a4 = *(const bf16x8*)&wall[(size_t)(64 + n16) * 64 + kc * 32 + g * 8];
        #pragma unroll
        for (int nt = 0; nt < 4; ++nt) {
            int n = nt * 16 + n16;
            int phys = (kc * 4 + g) ^ (n & 7);
            bf16x8 bx = *(const bf16x8*)&fl[n][phys * 8];
            acc[nt] = __builtin_amdgcn_mfma_f32_16x16x32_bf16(a, bx, acc[nt], 0, 0, 0);
            if (nt == wv) acc4 = __builtin_amdgcn_mfma_f32_16x16x32_bf16(a4, bx, acc4, 0, 0, 0);
        }
    }

    #pragma unroll
    for (int nt = 0; nt < 4; ++nt) {
        int pix = h * 64 + nt * 16 + n16;
        #pragma unroll
        for (int r = 0; r < 4; ++r) {
            int co = wv * 16 + g * 4 + r;
            short val = f2bs(acc[nt][r] + ball[co]);
            if (co < 8)       q[((size_t)(b * 8 + co)) * NPIX + pix] = val;
            else if (co < 16) k[((size_t)(b * 8 + co - 8)) * NPIX + pix] = val;
            else              v[((size_t)(b * 64 + co - 16)) * NPIX + pix] = val;
        }
    }
    {
        int pix = h * 64 + wv * 16 + n16;
        #pragma unroll
        for (int r = 0; r < 4; ++r) {
            int co = 64 + g * 4 + r;
            v[((size_t)(b * 64 + co - 16)) * NPIX + pix] = f2bs(acc4[r] + ball[co]);
        }
    }
}

// CAM gram partials body (256 virtual blocks)
__device__ __forceinline__ void gram_body(const float* __restrict__ f,
                                          float* __restrict__ gp, int blk, int t) {
    __shared__ __align__(16) float fl[64 * 68];
    int b = blk >> 6, nc = blk & 63;
    int n0 = nc * 64;
    int c = t & 63, dg = t >> 6;
    float acc[16];
    #pragma unroll
    for (int i = 0; i < 16; ++i) acc[i] = 0.f;
    for (int idx = t; idx < 4096; idx += 256) {
        int cc = idx >> 6, nn = idx & 63;
        fl[nn * 68 + cc] = f[((size_t)b * 64 + cc) * NPIX + n0 + nn];
    }
    __syncthreads();
    for (int nn = 0; nn < 64; ++nn) {
        float fc = fl[nn * 68 + c];
        const float4* fd = (const float4*)(fl + nn * 68 + dg * 16);
        #pragma unroll
        for (int k4 = 0; k4 < 4; ++k4) {
            float4 vv = fd[k4];
            acc[k4 * 4 + 0] += fc * vv.x;
            acc[k4 * 4 + 1] += fc * vv.y;
            acc[k4 * 4 + 2] += fc * vv.z;
            acc[k4 * 4 + 3] += fc * vv.w;
        }
    }
    float* dst = gp + (size_t)nc * 16384 + ((size_t)b * 64 + c) * 64 + dg * 16;
    #pragma unroll
    for (int kk = 0; kk < 16; ++kk) dst[kk] = acc[kk];
}

// fused qkv + gram (both read feat1 only)
__global__ __launch_bounds__(256) void k_qkvgram(const float* __restrict__ feat1,
                                                 const short* __restrict__ wall,
                                                 const float* __restrict__ ball,
                                                 short* q, short* k, short* v,
                                                 float* gp) {
    int blk = blockIdx.x, t = threadIdx.x;
    if (blk < 256) qkv_body(feat1, wall, ball, q, k, v, blk, t);
    else gram_body(feat1, gp, blk - 256, t);
}

// PAM partial pass (round-15 passing version): 128-wide j rounds, swapped QK,
// direct-global V, kl[128][20], pl[64][128] XOR-swizzled, setprio around MFMA.
__global__ __launch_bounds__(256) void k_pampart(const short* __restrict__ q,
                                                 const short* __restrict__ k,
                                                 const short* __restrict__ v,
                                                 short* __restrict__ po,
                                                 float* __restrict__ pl_acc) {
    __shared__ short kl[128][20];                // [j][d0..15 + pad]; 40B rows
    __shared__ __align__(16) short pl[64][128];  // [i][j], unit-swizzled

    int t = threadIdx.x;
    int lane = t & 63, w = t >> 6;
    int blk = blockIdx.x;
    int jc = blk >> 8, b = (blk >> 6) & 3, ic = blk & 63;
    int i0 = ic * 64;
    int n16 = lane & 15, g = lane >> 4;
    int key = n16 & 7;

    const short* qb = q + (size_t)b * 8 * NPIX;
    const short* kb = k + (size_t)b * 8 * NPIX;
    const short* vb = v + (size_t)b * 64 * NPIX;

    #pragma unroll
    for (int i = 0; i < 2; ++i) {
        int idx = i * 256 + t;
        int jj = idx & 127, dz = 8 + ((idx >> 7) << 1);
        *(unsigned*)&kl[jj][dz] = 0u;
    }

    bf16x8 aq = {};
    if (lane < 16) {
        int irow = i0 + w * 16 + lane;
        #pragma unroll
        for (int e = 0; e < 8; ++e) aq[e] = qb[(size_t)e * NPIX + irow];
    }

    f32x4 acc[4];
    #pragma unroll
    for (int i = 0; i < 4; ++i) acc[i] = (f32x4){0.f, 0.f, 0.f, 0.f};
    float lacc = 0.f;
    const f32x4 zz = {0.f, 0.f, 0.f, 0.f};

    for (int ro = 0; ro < 8; ++ro) {
        int j0 = jc * 1024 + ro * 128;
        #pragma unroll
        for (int i = 0; i < 2; ++i) {
            int idx = i * 256 + t;
            int jj = idx & 127, dp2 = idx >> 7;
            unsigned lo = (unsigned short)kb[(size_t)(dp2 * 2) * NPIX + j0 + jj];
            unsigned hi = (unsigned short)kb[(size_t)(dp2 * 2 + 1) * NPIX + j0 + jj];
            *(unsigned*)&kl[jj][dp2 * 2] = lo | (hi << 16);
        }
        bf16x8 av[4];
        #pragma unroll
        for (int ks = 0; ks < 4; ++ks)
            av[ks] = *(const bf16x8*)&vb[(size_t)(w * 16 + n16) * NPIX + j0 + ks * 32 + g * 8];
        __syncthreads();

        __builtin_amdgcn_s_setprio(1);
        #pragma unroll
        for (int jsub = 0; jsub < 8; ++jsub) {
            bf16x8 bk = {};
            if (lane < 32) {
                bf16x4 lo = *(const bf16x4*)&kl[jsub * 16 + n16][g * 8];
                bf16x4 hi = *(const bf16x4*)&kl[jsub * 16 + n16][g * 8 + 4];
                bk = __builtin_shufflevector(lo, hi, 0, 1, 2, 3, 4, 5, 6, 7);
            }
            f32x4 s = __builtin_amdgcn_mfma_f32_16x16x32_bf16(bk, aq, zz, 0, 0, 0);
            float e0 = exp2f(s[0]), e1 = exp2f(s[1]), e2 = exp2f(s[2]), e3 = exp2f(s[3]);
            lacc += (e0 + e1) + (e2 + e3);
            bf16x4 pk = { f2bs(e0), f2bs(e1), f2bs(e2), f2bs(e3) };
            int uw = (jsub * 2 + (g >> 1)) ^ key;
            *(bf16x4*)&pl[w * 16 + n16][uw * 8 + (g & 1) * 4] = pk;
        }
        __builtin_amdgcn_s_setprio(0);
        __syncthreads();

        __builtin_amdgcn_s_setprio(1);
        #pragma unroll
        for (int isub = 0; isub < 4; ++isub) {
            #pragma unroll
            for (int ks = 0; ks < 4; ++ks) {
                int ur = (ks * 4 + g) ^ key;
                bf16x8 bp = *(const bf16x8*)&pl[isub * 16 + n16][ur * 8];
                acc[isub] = __builtin_amdgcn_mfma_f32_16x16x32_bf16(av[ks], bp, acc[isub], 0, 0, 0);
            }
        }
        __builtin_amdgcn_s_setprio(0);
        __syncthreads();
    }

    {
        float lv = lacc;
        lv += __shfl_xor(lv, 16);
        lv += __shfl_xor(lv, 32);
        if (lane < 16)
            atomicAdd(&pl_acc[b * NPIX + i0 + w * 16 + lane], lv);
    }

    #pragma unroll
    for (int isub = 0; isub < 4; ++isub) {
        #pragma unroll
        for (int r = 0; r < 4; ++r) {
            int c = w * 16 + g * 4 + r;
            size_t o = ((size_t)((jc * BB + b) * 64 + c)) * NPIX + i0 + isub * 16 + n16;
            po[o] = f2bs(acc[isub][r]);
        }
    }
}

// fused gram-reduce + channel softmax
__global__ void k_camsm2(const float* __restrict__ gp, float* __restrict__ cattn) {
    int row = blockIdx.x;
    int d = threadIdx.x;
    float v = 0.f;
    #pragma unroll 8
    for (int p = 0; p < 64; ++p) v += gp[(size_t)p * 16384 + row * 64 + d];
    float mn = v;
    for (int s = 32; s; s >>= 1) mn = fminf(mn, __shfl_xor(mn, s));
    float e = exp2f((mn - v) * LOG2E);
    float sum = e;
    for (int s = 32; s; s >>= 1) sum += __shfl_xor(sum, s);
    cattn[(size_t)row * 64 + d] = e / sum;
}

// out = w8 @ (sa_conv + sc_conv) + b8 via MFMA (1x1, 64 -> 256)
__global__ __launch_bounds__(256) void k_finalmfma(const float* __restrict__ sa,
                                                   const float* __restrict__ sc,
                                                   const short* __restrict__ w8p,
                                                   const float* __restrict__ b8,
                                                   float* __restrict__ out) {
    __shared__ __align__(16) short fl[64][64];
    int t = threadIdx.x;
    int lane = t & 63, wv = t >> 6;
    int blk = blockIdx.x;
    int h = blk & 63, b = (blk >> 6) & 3, cq = blk >> 8;
    int n16 = lane & 15, g = lane >> 4;

    {
        int n = t & 63, ug2 = t >> 6;
        const float* sap = sa + ((size_t)b * CI) * NPIX + h * 64 + n;
        const float* scp = sc + ((size_t)b * CI) * NPIX + h * 64 + n;
        #pragma unroll
        for (int uu = 0; uu < 2; ++uu) {
            int u = ug2 + uu * 4;
            int ci0 = u * 8;
            short tmp[8];
            #pragma unroll
            for (int j = 0; j < 8; ++j) {
                size_t o = (size_t)(ci0 + j) * NPIX;
                tmp[j] = f2bs(sap[o] + scp[o]);
            }
            int phys = u ^ (n & 7);
            *(bf16x8*)&fl[n][phys * 8] = *(bf16x8*)tmp;
        }
    }
    __syncthreads();

    f32x4 acc[4];
    #pragma unroll
    for (int i = 0; i < 4; ++i) acc[i] = (f32x4){0.f, 0.f, 0.f, 0.f};
    int cobase = cq * 64 + wv * 16;

    #pragma unroll
    for (int kc = 0; kc < 2; ++kc) {
        bf16x8 a = *(const bf16x8*)&w8p[(size_t)(cobase + n16) * 64 + kc * 32 + g * 8];
        #pragma unroll
        for (int nt = 0; nt < 4; ++nt) {
            int n = nt * 16 + n16;
            int phys = (kc * 4 + g) ^ (n & 7);
            bf16x8 bx = *(const bf16x8*)&fl[n][phys * 8];
            acc[nt] = __builtin_amdgcn_mfma_f32_16x16x32_bf16(a, bx, acc[nt], 0, 0, 0);
        }
    }

    #pragma unroll
    for (int nt = 0; nt < 4; ++nt) {
        #pragma unroll
        for (int r = 0; r < 4; ++r) {
            int co = cobase + g * 4 + r;
            out[((size_t)(b * COUT + co)) * NPIX + h * 64 + nt * 16 + n16] = acc[nt][r] + b8[co];
        }
    }
}

// ---------------- launcher ----------------
extern "C" void kernel_launch(void* const* d_in, const int* in_sizes, int n_in,
                              void* d_out, int out_size, void* d_ws, size_t ws_size,
                              hipStream_t stream) {
    (void)in_sizes; (void)n_in; (void)out_size; (void)ws_size;
    const float* x    = (const float*)d_in[0];
    const float* w1   = (const float*)d_in[1];
    const float* bng  = (const float*)d_in[2];
    const float* bnb  = (const float*)d_in[3];
    const float* wq   = (const float*)d_in[4];
    const float* bq   = (const float*)d_in[5];
    const float* wk   = (const float*)d_in[6];
    const float* bk   = (const float*)d_in[7];
    const float* wv   = (const float*)d_in[8];
    const float* bv   = (const float*)d_in[9];
    const float* gpam = (const float*)d_in[10];
    const float* gcam = (const float*)d_in[11];
    const float* w2   = (const float*)d_in[12];
    const float* w8   = (const float*)d_in[13];
    const float* b8   = (const float*)d_in[14];
    float* out = (float*)d_out;

    char* WB = (char*)d_ws;
    float* fC1P0   = (float*)(WB + B_Y1V);            // conv1 p0
    float* fC1P1   = (float*)(WB + B_SACONV);         // conv1 p1
    float* fGP     = (float*)(WB + B_SACONV);         // gram partials (4MB, after C1P1 dies)
    short* fV      = (short*)(WB + B_Y1V);            // V bf16 (2MB)
    short* fSPREPSC= (short*)(WB + B_Y1V + 0x200000); // sc-prep bf16 (2MB)
    short* fSAPREP = (short*)(WB + B_Y1V);            // sa-prep bf16 (2MB, after V dies)
    float* fFEAT1  = (float*)(WB + B_FEAT1);
    short* fXPREP  = (short*)(WB + B_SA);             // 8MB spanning SA+Y2
    float* fC2B1   = (float*)(WB + B_SA);             // conv2b p1; SCCONV in-place
    short* fPO     = (short*)(WB + B_Y2);             // 8MB spanning Y2+SACONV
    float* fC2A0   = (float*)(WB + B_Y2);             // conv2a p0
    float* fC2B0   = (float*)(WB + B_FEAT1);          // conv2b p0 (feat1 dead)
    float* fC2A1   = (float*)(WB + B_SACONV);         // conv2a p1; SACONV in-place
    short* fQ      = (short*)(WB + B_Q);
    short* fK      = (short*)(WB + B_K);
    float* fST     = (float*)(WB + B_ST);
    float* fST2a   = fST + 128;
    float* fST2b   = fST + 256;
    float* fCATT   = (float*)(WB + B_CATT);
    short* fWP1    = (short*)(WB + B_WP1);
    short* fWP2    = (short*)(WB + B_WP2);
    float* fPL     = (float*)(WB + B_PL);
    short* fW8P    = (short*)(WB + B_W8P);
    short* fWQKV   = (short*)(WB + B_WQKV);
    float* fBALL   = (float*)(WB + B_BALL);

    k_prepw<<<1382, 256, 0, stream>>>(x, w1, w2, w8, wq, bq, wk, bk, wv, bv,
                                      fXPREP, fWP1, fWP2, fW8P, fWQKV, fBALL, fST, fPL);

    k_convmfma<8><<<512, 256, 0, stream>>>(fXPREP, fWP1, fC1P0, fC1P1);
    k_bnstats<<<1024, 256, 0, stream>>>(fC1P0, fC1P1, fST);
    k_bnapply2<<<4096, 256, 0, stream>>>(fC1P0, fC1P1, fST, bng, bnb, fFEAT1);

    k_qkvgram<<<512, 256, 0, stream>>>(fFEAT1, fWQKV, fBALL, fQ, fK, fV, fGP);
    k_camsm2<<<256, 64, 0, stream>>>(fGP, fCATT);        // GP consumed before PO clobbers it

    k_pampart<<<1024, 256, 0, stream>>>(fQ, fK, fV, fPO, fPL);
    k_campam<<<384, 256, 0, stream>>>(fCATT, fFEAT1, gcam, fSPREPSC, fPO, fPL, gpam, fSAPREP);

    k_conv2x<<<1024, 256, 0, stream>>>(fSAPREP, fSPREPSC, fWP2, fC2A0, fC2A1, fC2B0, fC2B1);
    k_bnstats2x<<<2048, 256, 0, stream>>>(fC2A0, fC2A1, fC2B0, fC2B1, fST2a, fST2b);
    k_bnapply2x<<<8192, 256, 0, stream>>>(fC2A0, fC2A1, fC2B0, fC2B1, fST2a, fST2b,
                                          bng, bnb, fC2A1, fC2B1);

    k_finalmfma<<<1024, 256, 0, stream>>>(fC2A1, fC2B1, fW8P, b8, out);
}